// Round 14
// baseline (1304.943 us; speedup 1.0000x reference)
//
#include <hip/hip_runtime.h>
#include <math.h>

#define VOCAB 65
#define NBATCH 256

typedef __attribute__((ext_vector_type(8))) short bf16x8;
typedef __attribute__((ext_vector_type(4))) float f32x4;

#define MFMA16(a, b, c) __builtin_amdgcn_mfma_f32_16x16x32_bf16((a), (b), (c), 0, 0, 0)

__device__ __forceinline__ unsigned short f2b(float f) {
    union { float f; unsigned u; } v; v.f = f;
    unsigned r = (v.u + 0x7fffu + ((v.u >> 16) & 1u)) >> 16;
    return (unsigned short)r;
}
__device__ __forceinline__ unsigned cvtpk(float lo, float hi) {
    unsigned r; asm("v_cvt_pk_bf16_f32 %0, %1, %2" : "=v"(r) : "v"(lo), "v"(hi)); return r;
}
__device__ __forceinline__ unsigned short f2b1(float v) { return (unsigned short)cvtpk(v, v); }
__device__ __forceinline__ float b2f(unsigned short h) {
    union { unsigned u; float f; } v; v.u = ((unsigned)h) << 16; return v.f;
}
__device__ __forceinline__ float lo2f(unsigned wd) {
    union { unsigned u; float f; } v; v.u = wd << 16; return v.f;
}
__device__ __forceinline__ float hi2f(unsigned wd) {
    union { unsigned u; float f; } v; v.u = wd & 0xffff0000u; return v.f;
}
// balanced interleaved tile set: half h owns i-tiles TS(h,0..7); both halves sum to 68 chunks
__device__ __forceinline__ int TS(int h, int j) {
    return (j & 1) ? (16 - j - h) : (j + h);
}

// wbuf layout (shorts): wqkvt 6*[3][64][64] @0 ; wot 6*[64][64] @73728 ;
// w1t 6*[256][64] @98304 ; w2t 6*[64][256] @196608 ; woutt [80][64] @294912 ;
// PE table (float[256][64]) @short-offset 300032
__global__ __launch_bounds__(256)
void prep_kernel(const float* __restrict__ Wq, const float* __restrict__ Wk,
                 const float* __restrict__ Wv, const float* __restrict__ Wo,
                 const float* __restrict__ W1, const float* __restrict__ W2,
                 const float* __restrict__ Wout, unsigned short* __restrict__ wbuf) {
    int l = blockIdx.y;
    int idx = blockIdx.x * 256 + threadIdx.x;
    if (l < 6) {
        float v; unsigned short* dst;
        if (idx < 12288) {
            int mat = idx >> 12, m = (idx >> 6) & 63, k = idx & 63;
            const float* W = mat == 0 ? Wq : (mat == 1 ? Wk : Wv);
            v = W[l * 4096 + k * 64 + m];
            dst = wbuf + l * 12288 + idx;
        } else if (idx < 16384) {
            int j = idx - 12288; int m = j >> 6, k = j & 63;
            v = Wo[l * 4096 + k * 64 + m];
            dst = wbuf + 73728 + l * 4096 + j;
        } else if (idx < 32768) {
            int j = idx - 16384; int m = j >> 6, k = j & 63;
            v = W1[l * 16384 + k * 256 + m];
            dst = wbuf + 98304 + l * 16384 + j;
        } else {
            int j = idx - 32768; int m = j >> 8, k = j & 255;
            v = W2[l * 16384 + k * 64 + m];
            dst = wbuf + 196608 + l * 16384 + j;
        }
        *dst = f2b(v);
    } else {
        if (idx < 5120) {
            int m = idx >> 6, k = idx & 63;
            float v = (m < 65) ? Wout[k * 65 + m] : 0.f;
            wbuf[294912 + idx] = f2b(v);
        } else if (idx < 21504) {
            int j = idx - 5120; int t = j >> 6, e = j & 63;
            int i2 = e >> 1;
            float div = expf(-(float)(2 * i2) * 0.14391156831212788f);
            float ang = (float)t * div;
            ((float*)(wbuf + 300032))[j] = (e & 1) ? cosf(ang) : sinf(ang);
        }
    }
}

// ---------------- transformer: 2 blocks / batch element (sequence split), 8 waves each ----
// Block 2b+half owns query-row tiles TS(half, 0..7); computes K/V for ALL rows (redundant).
// Cross-block: post-LN2 x exchanged via global xg (parity slots) + flag counter (device scope).
// LDS (bytes): xb[256][72] @0 ; C overlay @36864: {q2[128][24] | +k2[256][24]@43008 |
//   +vt[16][264]@55296} or proj[128][72] or hb[128][136] ; red[8] @71680. Total 71712 (<80K => 2/CU).
__global__ __launch_bounds__(512, 4)
void tf_kernel(const int* __restrict__ inp, const int* __restrict__ labels,
               const float* __restrict__ emb,
               const float* __restrict__ bq, const float* __restrict__ bk,
               const float* __restrict__ bv, const float* __restrict__ bo,
               const float* __restrict__ ln1g, const float* __restrict__ ln1b,
               const float* __restrict__ ln2g, const float* __restrict__ ln2b,
               const float* __restrict__ b1, const float* __restrict__ b2,
               const float* __restrict__ bout,
               const unsigned short* __restrict__ wbuf,
               int* __restrict__ flags, unsigned short* __restrict__ xg,
               float* __restrict__ out_logits, float* __restrict__ partials) {
    __shared__ __attribute__((aligned(16))) char smem[71712];
    unsigned short (*xb)[72]   = (unsigned short (*)[72])(smem);
    unsigned short (*q2)[24]   = (unsigned short (*)[24])(smem + 36864);
    unsigned short (*k2)[24]   = (unsigned short (*)[24])(smem + 43008);
    unsigned short (*vt)[264]  = (unsigned short (*)[264])(smem + 55296);
    unsigned short (*proj)[72] = (unsigned short (*)[72])(smem + 36864);
    unsigned short (*hbuf)[136]= (unsigned short (*)[136])(smem + 36864);
    float* red = (float*)(smem + 71680);

    const unsigned short* wqkvt = wbuf;
    const unsigned short* wot   = wbuf + 73728;
    const unsigned short* w1t   = wbuf + 98304;
    const unsigned short* w2t   = wbuf + 196608;
    const unsigned short* woutt = wbuf + 294912;
    const float* pef = (const float*)(wbuf + 300032);

    const int bp   = blockIdx.x >> 1;    // batch element
    const int half = blockIdx.x & 1;     // sequence half (interleaved tiles)
    const int tid = threadIdx.x;
    const int w = tid >> 6;              // 0..7
    const int lane = tid & 63;
    const int cc = lane & 15;
    const int gg = lane >> 4;

    const bf16x8 zf = {0, 0, 0, 0, 0, 0, 0, 0};
    const bf16x8 ones = {(short)0x3F80, (short)0x3F80, (short)0x3F80, (short)0x3F80,
                         (short)0x3F80, (short)0x3F80, (short)0x3F80, (short)0x3F80};

    // bpermute source addrs for P redistribution (constant per lane)
    const int srcA = ((gg & 1) * 32 + cc) * 4;
    const int srcB = srcA + 64;

    unsigned rr[8];   // residual, own rows: row tid>>2, cols 16*(tid&3)+0..15
    const int lr = tid >> 2, qq = tid & 3;
    const int gr = 16 * TS(half, lr >> 4) + (lr & 15);   // own global row for this thread

    // ---------- embed + positional: full 256 rows (redundant), own rows -> rr ----------
    #pragma unroll
    for (int it = 0; it < 2; ++it) {
        int r = lr + 128 * it;
        int id = inp[bp * 256 + r];
        const float4* er = (const float4*)(emb + id * 64 + 16 * qq);
        const float4* pr = (const float4*)(pef + r * 64 + 16 * qq);
        unsigned nw[8];
        #pragma unroll
        for (int j = 0; j < 4; ++j) {
            float4 ev = er[j], pv = pr[j];
            nw[2 * j]     = cvtpk(ev.x + pv.x, ev.y + pv.y);
            nw[2 * j + 1] = cvtpk(ev.z + pv.z, ev.w + pv.w);
        }
        *(uint4*)&xb[r][16 * qq]     = make_uint4(nw[0], nw[1], nw[2], nw[3]);
        *(uint4*)&xb[r][16 * qq + 8] = make_uint4(nw[4], nw[5], nw[6], nw[7]);
    }
    __syncthreads();
    {   // own rows -> rr (read back)
        uint4 a = *(const uint4*)&xb[gr][16 * qq];
        uint4 c = *(const uint4*)&xb[gr][16 * qq + 8];
        rr[0] = a.x; rr[1] = a.y; rr[2] = a.z; rr[3] = a.w;
        rr[4] = c.x; rr[5] = c.y; rr[6] = c.z; rr[7] = c.w;
    }

    // owner-pass: x = LN(rr + proj) -> rr, xb (own 128 rows; 4 threads/row)
    auto ownerLN = [&](const float* gp_, const float* bp_) {
        uint4 p0 = *(const uint4*)&proj[lr][16 * qq];
        uint4 p1 = *(const uint4*)&proj[lr][16 * qq + 8];
        unsigned pw[8] = {p0.x, p0.y, p0.z, p0.w, p1.x, p1.y, p1.z, p1.w};
        float xv[16];
        float s = 0.f, s2 = 0.f;
        #pragma unroll
        for (int j = 0; j < 8; ++j) {
            float x0 = lo2f(rr[j]) + lo2f(pw[j]);
            float x1 = hi2f(rr[j]) + hi2f(pw[j]);
            xv[2 * j] = x0; xv[2 * j + 1] = x1;
            s += x0 + x1; s2 += x0 * x0 + x1 * x1;
        }
        s  += __shfl_xor(s, 1, 64);  s  += __shfl_xor(s, 2, 64);
        s2 += __shfl_xor(s2, 1, 64); s2 += __shfl_xor(s2, 2, 64);
        float mu = s * 0.015625f;
        float var = s2 * 0.015625f - mu * mu;
        float rstd = rsqrtf(var + 1e-5f);
        const float4* gp = (const float4*)(gp_ + 16 * qq);
        const float4* bp4 = (const float4*)(bp_ + 16 * qq);
        #pragma unroll
        for (int j = 0; j < 4; ++j) {
            float4 gv = gp[j], bv2 = bp4[j];
            float n0 = (xv[4 * j]     - mu) * rstd * gv.x + bv2.x;
            float n1 = (xv[4 * j + 1] - mu) * rstd * gv.y + bv2.y;
            float n2 = (xv[4 * j + 2] - mu) * rstd * gv.z + bv2.z;
            float n3 = (xv[4 * j + 3] - mu) * rstd * gv.w + bv2.w;
            rr[2 * j]     = cvtpk(n0, n1);
            rr[2 * j + 1] = cvtpk(n2, n3);
        }
        *(uint4*)&xb[gr][16 * qq]     = make_uint4(rr[0], rr[1], rr[2], rr[3]);
        *(uint4*)&xb[gr][16 * qq + 8] = make_uint4(rr[4], rr[5], rr[6], rr[7]);
    };

    for (int l = 0; l < 6; ++l) {
        const unsigned short* Wqkv = wqkvt + l * 12288;

        // hoist A-frags: K/V m-tiles {2w, 2w+1} (all rows) + Q m-tile TS(half, w) (own)
        bf16x8 afk00 = *(const bf16x8*)&xb[16 * (2 * w)     + cc][8 * gg];
        bf16x8 afk01 = *(const bf16x8*)&xb[16 * (2 * w)     + cc][32 + 8 * gg];
        bf16x8 afk10 = *(const bf16x8*)&xb[16 * (2 * w + 1) + cc][8 * gg];
        bf16x8 afk11 = *(const bf16x8*)&xb[16 * (2 * w + 1) + cc][32 + 8 * gg];
        const int gq = TS(half, w);
        bf16x8 afq0 = *(const bf16x8*)&xb[16 * gq + cc][8 * gg];
        bf16x8 afq1 = *(const bf16x8*)&xb[16 * gq + cc][32 + 8 * gg];

        // ================= attention: 4 phases (head pairs) =================
        #pragma unroll
        for (int p = 0; p < 4; ++p) {
            if (p) __syncthreads();   // prev phase's q2/k2/vt reads done
            {   // Q for own tile (local slot w)
                const unsigned short* Wt = Wqkv;
                bf16x8 bf0 = *(const bf16x8*)&Wt[(16 * p + cc) * 64 + 8 * gg];
                bf16x8 bf1 = *(const bf16x8*)&Wt[(16 * p + cc) * 64 + 32 + 8 * gg];
                float bb = bq[l * 64 + 16 * p + cc];
                f32x4 c = {0.f, 0.f, 0.f, 0.f};
                c = MFMA16(afq0, bf0, c);
                c = MFMA16(afq1, bf1, c);
                #pragma unroll
                for (int r = 0; r < 4; ++r)
                    q2[16 * w + 4 * gg + r][cc] = f2b1((c[r] + bb) * 0.35355339059327373f);
            }
            #pragma unroll
            for (int mat = 1; mat < 3; ++mat) {   // K, V for ALL rows
                const unsigned short* Wt = Wqkv + mat * 4096;
                bf16x8 bf0 = *(const bf16x8*)&Wt[(16 * p + cc) * 64 + 8 * gg];
                bf16x8 bf1 = *(const bf16x8*)&Wt[(16 * p + cc) * 64 + 32 + 8 * gg];
                const float* bias = (mat == 1 ? bk : bv) + l * 64;
                float bb = bias[16 * p + cc];
                #pragma unroll
                for (int mi = 0; mi < 2; ++mi) {
                    int mt = 2 * w + mi;
                    f32x4 c = {0.f, 0.f, 0.f, 0.f};
                    c = MFMA16(mi ? afk10 : afk00, bf0, c);
                    c = MFMA16(mi ? afk11 : afk01, bf1, c);
                    if (mat == 1) {
                        #pragma unroll
                        for (int r = 0; r < 4; ++r)
                            k2[16 * mt + 4 * gg + r][cc] = f2b1(c[r] + bb);
                    } else {
                        uint2 pk;
                        pk.x = cvtpk(c[0] + bb, c[1] + bb);
                        pk.y = cvtpk(c[2] + bb, c[3] + bb);
                        *(uint2*)&vt[cc][16 * mt + 4 * gg] = pk;
                    }
                }
            }
            __syncthreads();   // q2/k2/vt ready

            #pragma unroll
            for (int hh = 0; hh < 2; ++hh) {
                const int h = 2 * p + hh;
                const int hoff = 8 * hh;
                int lt = (w + h) & 7;            // local q-tile slot
                int i = TS(half, lt);            // global i-tile
                bf16x8 qf = zf;
                if (gg == 0) qf = *(const bf16x8*)&q2[16 * lt + cc][hoff];
                f32x4 o = {0.f, 0.f, 0.f, 0.f};
                int full = i >> 1;
                for (int jc = 0; jc < full; ++jc) {
                    uint2 pk0, pk1;
                    {
                        bf16x8 kf = zf;
                        if (gg == 0) kf = *(const bf16x8*)&k2[16 * (2 * jc) + cc][hoff];
                        f32x4 sc = {0.f, 0.f, 0.f, 0.f};
                        sc = MFMA16(kf, qf, sc);
                        pk0.x = cvtpk(__expf(sc[0]), __expf(sc[1]));
                        pk0.y = cvtpk(__expf(sc[2]), __expf(sc[3]));
                    }
                    {
                        bf16x8 kf = zf;
                        if (gg == 0) kf = *(const bf16x8*)&k2[16 * (2 * jc + 1) + cc][hoff];
                        f32x4 sc = {0.f, 0.f, 0.f, 0.f};
                        sc = MFMA16(kf, qf, sc);
                        pk1.x = cvtpk(__expf(sc[0]), __expf(sc[1]));
                        pk1.y = cvtpk(__expf(sc[2]), __expf(sc[3]));
                    }
                    unsigned px = (gg >= 2) ? pk1.x : pk0.x;
                    unsigned py = (gg >= 2) ? pk1.y : pk0.y;
                    unsigned w0 = __builtin_amdgcn_ds_bpermute(srcA, px);
                    unsigned w1 = __builtin_amdgcn_ds_bpermute(srcA, py);
                    unsigned w2 = __builtin_amdgcn_ds_bpermute(srcB, px);
                    unsigned w3 = __builtin_amdgcn_ds_bpermute(srcB, py);
                    union { uint4 u; bf16x8 v; } pa_u;
                    pa_u.u = make_uint4(w0, w1, w2, w3);
                    bf16x8 vb;
                    if (cc < 8)       vb = *(const bf16x8*)&vt[hoff + cc][32 * jc + 8 * gg];
                    else if (cc == 8) vb = ones;
                    else              vb = zf;
                    o = MFMA16(pa_u.v, vb, o);
                }
                {   // tail chunk (diagonal)
                    int jc = full;
                    uint2 pk0 = make_uint2(0u, 0u), pk1 = make_uint2(0u, 0u);
                    {
                        int jt = 2 * jc;
                        bf16x8 kf = zf;
                        if (gg == 0) kf = *(const bf16x8*)&k2[16 * jt + cc][hoff];
                        f32x4 sc = {0.f, 0.f, 0.f, 0.f};
                        sc = MFMA16(kf, qf, sc);
                        float pv[4];
                        #pragma unroll
                        for (int r = 0; r < 4; ++r) {
                            float pp = __expf(sc[r]);
                            if (jt == i && 4 * gg + r > cc) pp = 0.f;
                            pv[r] = pp;
                        }
                        pk0.x = cvtpk(pv[0], pv[1]);
                        pk0.y = cvtpk(pv[2], pv[3]);
                    }
                    if (2 * jc + 1 <= i) {
                        int jt = 2 * jc + 1;
                        bf16x8 kf = zf;
                        if (gg == 0) kf = *(const bf16x8*)&k2[16 * jt + cc][hoff];
                        f32x4 sc = {0.f, 0.f, 0.f, 0.f};
                        sc = MFMA16(kf, qf, sc);
                        float pv[4];
                        #pragma unroll
                        for (int r = 0; r < 4; ++r) {
                            float pp = __expf(sc[r]);
                            if (jt == i && 4 * gg + r > cc) pp = 0.f;
                            pv[r] = pp;
                        }
                        pk1.x = cvtpk(pv[0], pv[1]);
                        pk1.y = cvtpk(pv[2], pv[3]);
                    }
                    unsigned px = (gg >= 2) ? pk1.x : pk0.x;
                    unsigned py = (gg >= 2) ? pk1.y : pk0.y;
                    unsigned w0 = __builtin_amdgcn_ds_bpermute(srcA, px);
                    unsigned w1 = __builtin_amdgcn_ds_bpermute(srcA, py);
                    unsigned w2 = __builtin_amdgcn_ds_bpermute(srcB, px);
                    unsigned w3 = __builtin_amdgcn_ds_bpermute(srcB, py);
                    union { uint4 u; bf16x8 v; } pa_u;
                    pa_u.u = make_uint4(w0, w1, w2, w3);
                    bf16x8 vb;
                    if (cc < 8)       vb = *(const bf16x8*)&vt[hoff + cc][32 * jc + 8 * gg];
                    else if (cc == 8) vb = ones;
                    else              vb = zf;
                    o = MFMA16(pa_u.v, vb, o);
                }
                // normalize + write O into xb (own global rows)
                #pragma unroll
                for (int r = 0; r < 4; ++r) {
                    float rs = __shfl(o[r], (lane & 48) + 8, 64);
                    float ov = o[r] * __builtin_amdgcn_rcpf(rs);
                    if (cc < 8)
                        xb[16 * i + 4 * gg + r][8 * h + cc] = f2b1(ov);
                }
            }
        }
        __syncthreads();   // attention done; C region free; O complete in xb own rows

        // ================= Wo projection (own rows) -> proj =================
        {
            const unsigned short* Wt = wot + l * 4096;
            int n = w & 3;
            bf16x8 bf0 = *(const bf16x8*)&Wt[(16 * n + cc) * 64 + 8 * gg];
            bf16x8 bf1 = *(const bf16x8*)&Wt[(16 * n + cc) * 64 + 32 + 8 * gg];
            float bb = bo[l * 64 + 16 * n + cc];
            #pragma unroll
            for (int t = 0; t < 4; ++t) {
                int lt = 4 * (w >> 2) + t;
                int gi = TS(half, lt);
                bf16x8 o0 = *(const bf16x8*)&xb[16 * gi + cc][8 * gg];
                bf16x8 o1 = *(const bf16x8*)&xb[16 * gi + cc][32 + 8 * gg];
                f32x4 c = {0.f, 0.f, 0.f, 0.f};
                c = MFMA16(o0, bf0, c);
                c = MFMA16(o1, bf1, c);
                #pragma unroll
                for (int r = 0; r < 4; ++r)
                    proj[16 * lt + 4 * gg + r][16 * n + cc] = f2b1(c[r] + bb);
            }
        }
        __syncthreads();
        ownerLN(ln1g + l * 64, ln1b + l * 64);
        __syncthreads();

        // ================= FFN (own rows; 2 chunks of 128 hidden cols) =================
        f32x4 facc[4];
        #pragma unroll
        for (int t = 0; t < 4; ++t) facc[t] = {0.f, 0.f, 0.f, 0.f};
        #pragma unroll
        for (int ch = 0; ch < 2; ++ch) {
            if (ch) __syncthreads();   // WAR on hbuf
            {   // FFN1: wave w = n-tile; own 8 row-tiles
                const unsigned short* Wt = w1t + l * 16384;
                int gcol = 128 * ch + 16 * w + cc;
                bf16x8 bf0 = *(const bf16x8*)&Wt[gcol * 64 + 8 * gg];
                bf16x8 bf1 = *(const bf16x8*)&Wt[gcol * 64 + 32 + 8 * gg];
                float bb = b1[l * 256 + gcol];
                #pragma unroll
                for (int lt = 0; lt < 8; ++lt) {
                    int gi = TS(half, lt);
                    bf16x8 x0 = *(const bf16x8*)&xb[16 * gi + cc][8 * gg];
                    bf16x8 x1 = *(const bf16x8*)&xb[16 * gi + cc][32 + 8 * gg];
                    f32x4 c = {0.f, 0.f, 0.f, 0.f};
                    c = MFMA16(x0, bf0, c);
                    c = MFMA16(x1, bf1, c);
                    #pragma unroll
                    for (int r = 0; r < 4; ++r)
                        hbuf[16 * lt + 4 * gg + r][16 * w + cc] = f2b1(fmaxf(c[r] + bb, 0.f));
                }
            }
            __syncthreads();
            {   // FFN2 accumulate
                const unsigned short* Wt = w2t + l * 16384;
                int n = w & 3;
                #pragma unroll
                for (int ks = 0; ks < 4; ++ks) {
                    bf16x8 bf0 = *(const bf16x8*)&Wt[(16 * n + cc) * 256 + 128 * ch + 32 * ks + 8 * gg];
                    #pragma unroll
                    for (int t = 0; t < 4; ++t) {
                        int lt = 4 * (w >> 2) + t;
                        bf16x8 h0 = *(const bf16x8*)&hbuf[16 * lt + cc][32 * ks + 8 * gg];
                        facc[t] = MFMA16(h0, bf0, facc[t]);
                    }
                }
            }
        }
        __syncthreads();
        {   // FFN2 epilogue -> proj
            int n = w & 3;
            float bb = b2[l * 64 + 16 * n + cc];
            #pragma unroll
            for (int t = 0; t < 4; ++t) {
                int lt = 4 * (w >> 2) + t;
                #pragma unroll
                for (int r = 0; r < 4; ++r)
                    proj[16 * lt + 4 * gg + r][16 * n + cc] = f2b1(facc[t][r] + bb);
            }
        }
        __syncthreads();
        ownerLN(ln2g + l * 64, ln2b + l * 64);
        __syncthreads();

        // ================= x exchange (layers 0..4) =================
        if (l < 5) {
            unsigned short* xs = xg + ((size_t)(bp * 2 + (l & 1)) * 256) * 64;
            *(uint4*)&xs[gr * 64 + 16 * qq]     = make_uint4(rr[0], rr[1], rr[2], rr[3]);
            *(uint4*)&xs[gr * 64 + 16 * qq + 8] = make_uint4(rr[4], rr[5], rr[6], rr[7]);
            __threadfence();
            __syncthreads();
            if (tid == 0) {
                atomicAdd(&flags[bp], 1);
                long guard = 0;
                while (atomicAdd(&flags[bp], 0) < 2 * (l + 1) && guard < 200000000L) ++guard;
            }
            __syncthreads();
            __threadfence();
            {   // pull other half's rows into xb
                int go = 16 * TS(half ^ 1, lr >> 4) + (lr & 15);
                uint4 a = *(const uint4*)&xs[go * 64 + 16 * qq];
                uint4 c = *(const uint4*)&xs[go * 64 + 16 * qq + 8];
                *(uint4*)&xb[go][16 * qq]     = a;
                *(uint4*)&xb[go][16 * qq + 8] = c;
            }
            __syncthreads();
        }
    } // layers

    // ================= logits (own rows): wave w -> tile TS(half,w), n=0..4 ============
    {
        int gi = TS(half, w);
        bf16x8 a0 = *(const bf16x8*)&xb[16 * gi + cc][8 * gg];
        bf16x8 a1 = *(const bf16x8*)&xb[16 * gi + cc][32 + 8 * gg];
        #pragma unroll
        for (int n = 0; n < 5; ++n) {
            bf16x8 bf0 = *(const bf16x8*)&woutt[(16 * n + cc) * 64 + 8 * gg];
            bf16x8 bf1 = *(const bf16x8*)&woutt[(16 * n + cc) * 64 + 32 + 8 * gg];
            f32x4 c = {0.f, 0.f, 0.f, 0.f};
            c = MFMA16(a0, bf0, c);
            c = MFMA16(a1, bf1, c);
            int col = 16 * n + cc;
            if (col < 65) {
                float bb = bout[col];
                #pragma unroll
                for (int r = 0; r < 4; ++r) {
                    int grow = 16 * gi + 4 * gg + r;
                    float v = c[r] + bb;
                    out_logits[((size_t)bp * 256 + grow) * 65 + col] = v;
                    proj[16 * w + 4 * gg + r][col] = f2b1(v);
                }
            }
        }
    }
    __syncthreads();

    // ================= loss partial (own 128 rows; 4 threads/row) =================
    {
        float sum = 0.f;
        for (int c2 = qq; c2 < 65; c2 += 4) sum += __expf(b2f(proj[lr][c2]));
        sum += __shfl_xor(sum, 1, 64);
        sum += __shfl_xor(sum, 2, 64);
        float nll = 0.f;
        if (qq == 0) {
            int lab = labels[bp * 256 + gr];
            nll = logf(sum) - b2f(proj[lr][lab]);
        }
        #pragma unroll
        for (int m = 1; m < 64; m <<= 1) nll += __shfl_xor(nll, m, 64);
        if (lane == 0) red[w] = nll;
        __syncthreads();
        if (tid == 0) {
            float s = 0.f;
            #pragma unroll
            for (int i = 0; i < 8; ++i) s += red[i];
            partials[blockIdx.x] = s;
        }
    }
}

__global__ __launch_bounds__(64)
void loss_reduce(const float* __restrict__ partials, float* __restrict__ out) {
    int t = threadIdx.x;
    float s = 0.f;
    #pragma unroll
    for (int k = 0; k < 8; ++k) s += partials[t + 64 * k];
    #pragma unroll
    for (int m = 1; m < 64; m <<= 1) s += __shfl_xor(s, m, 64);
    if (t == 0) out[0] = s * (1.f / 65536.f);
}

// ---------------- host ----------------
extern "C" void kernel_launch(void* const* d_in, const int* in_sizes, int n_in,
                              void* d_out, int out_size, void* d_ws, size_t ws_size,
                              hipStream_t stream) {
    const int*   inputs = (const int*)d_in[0];
    const int*   labels = (const int*)d_in[1];
    const float* emb  = (const float*)d_in[2];
    const float* Wq   = (const float*)d_in[3];
    const float* bq   = (const float*)d_in[4];
    const float* Wk   = (const float*)d_in[5];
    const float* bk   = (const float*)d_in[6];
    const float* Wv   = (const float*)d_in[7];
    const float* bv   = (const float*)d_in[8];
    const float* Wo   = (const float*)d_in[9];
    const float* bo   = (const float*)d_in[10];
    const float* ln1g = (const float*)d_in[11];
    const float* ln1b = (const float*)d_in[12];
    const float* ln2g = (const float*)d_in[13];
    const float* ln2b = (const float*)d_in[14];
    const float* W1   = (const float*)d_in[15];
    const float* b1   = (const float*)d_in[16];
    const float* W2   = (const float*)d_in[17];
    const float* b2   = (const float*)d_in[18];
    const float* Wout = (const float*)d_in[19];
    const float* bout = (const float*)d_in[20];

    float* logits = (float*)d_out;
    float* loss   = logits + (size_t)65536 * 65;

    float* partials = (float*)d_ws;                                   // 512 f32
    int*   flags    = (int*)((char*)d_ws + 2048);                     // 256 i32
    unsigned short* wbuf = (unsigned short*)((char*)d_ws + 4096);     // 665600 B
    unsigned short* xg   = (unsigned short*)((char*)d_ws + 670720);   // 16.8 MB

    hipMemsetAsync(flags, 0, 256 * sizeof(int), stream);   // fresh pair-barrier counters
    prep_kernel<<<dim3(192, 7), 256, 0, stream>>>(Wq, Wk, Wv, Wo, W1, W2, Wout, wbuf);
    tf_kernel<<<512, 512, 0, stream>>>(inputs, labels, emb,
                                       bq, bk, bv, bo,
                                       ln1g, ln1b, ln2g, ln2b,
                                       b1, b2, bout,
                                       wbuf, flags, xg, logits, partials);
    loss_reduce<<<1, 64, 0, stream>>>(partials, loss);
}

// Round 15
// 1262.273 us; speedup vs baseline: 1.0338x; 1.0338x over previous
//
#include <hip/hip_runtime.h>
#include <math.h>

#define VOCAB 65
#define NBATCH 256

typedef __attribute__((ext_vector_type(8))) short bf16x8;
typedef __attribute__((ext_vector_type(4))) float f32x4;

#define MFMA16(a, b, c) __builtin_amdgcn_mfma_f32_16x16x32_bf16((a), (b), (c), 0, 0, 0)

__device__ __forceinline__ unsigned short f2b(float f) {
    union { float f; unsigned u; } v; v.f = f;
    unsigned r = (v.u + 0x7fffu + ((v.u >> 16) & 1u)) >> 16;
    return (unsigned short)r;
}
__device__ __forceinline__ unsigned cvtpk(float lo, float hi) {
    unsigned r; asm("v_cvt_pk_bf16_f32 %0, %1, %2" : "=v"(r) : "v"(lo), "v"(hi)); return r;
}
__device__ __forceinline__ unsigned short f2b1(float v) { return (unsigned short)cvtpk(v, v); }
__device__ __forceinline__ float b2f(unsigned short h) {
    union { unsigned u; float f; } v; v.u = ((unsigned)h) << 16; return v.f;
}
__device__ __forceinline__ float lo2f(unsigned wd) {
    union { unsigned u; float f; } v; v.u = wd << 16; return v.f;
}
__device__ __forceinline__ float hi2f(unsigned wd) {
    union { unsigned u; float f; } v; v.u = wd & 0xffff0000u; return v.f;
}
// balanced interleaved tile set: half h owns i-tiles TS(h,0..7); both halves sum to 68 chunks
__device__ __forceinline__ int TS(int h, int j) {
    return (j & 1) ? (16 - j - h) : (j + h);
}

// wbuf layout (shorts): wqkvt 6*[3][64][64] @0 ; wot 6*[64][64] @73728 ;
// w1t 6*[256][64] @98304 ; w2t 6*[64][256] @196608 ; woutt [80][64] @294912 ;
// PE table (float[256][64]) @short-offset 300032
__global__ __launch_bounds__(256)
void prep_kernel(const float* __restrict__ Wq, const float* __restrict__ Wk,
                 const float* __restrict__ Wv, const float* __restrict__ Wo,
                 const float* __restrict__ W1, const float* __restrict__ W2,
                 const float* __restrict__ Wout, unsigned short* __restrict__ wbuf) {
    int l = blockIdx.y;
    int idx = blockIdx.x * 256 + threadIdx.x;
    if (l < 6) {
        float v; unsigned short* dst;
        if (idx < 12288) {
            int mat = idx >> 12, m = (idx >> 6) & 63, k = idx & 63;
            const float* W = mat == 0 ? Wq : (mat == 1 ? Wk : Wv);
            v = W[l * 4096 + k * 64 + m];
            dst = wbuf + l * 12288 + idx;
        } else if (idx < 16384) {
            int j = idx - 12288; int m = j >> 6, k = j & 63;
            v = Wo[l * 4096 + k * 64 + m];
            dst = wbuf + 73728 + l * 4096 + j;
        } else if (idx < 32768) {
            int j = idx - 16384; int m = j >> 6, k = j & 63;
            v = W1[l * 16384 + k * 256 + m];
            dst = wbuf + 98304 + l * 16384 + j;
        } else {
            int j = idx - 32768; int m = j >> 8, k = j & 255;
            v = W2[l * 16384 + k * 64 + m];
            dst = wbuf + 196608 + l * 16384 + j;
        }
        *dst = f2b(v);
    } else {
        if (idx < 5120) {
            int m = idx >> 6, k = idx & 63;
            float v = (m < 65) ? Wout[k * 65 + m] : 0.f;
            wbuf[294912 + idx] = f2b(v);
        } else if (idx < 21504) {
            int j = idx - 5120; int t = j >> 6, e = j & 63;
            int i2 = e >> 1;
            float div = expf(-(float)(2 * i2) * 0.14391156831212788f);
            float ang = (float)t * div;
            ((float*)(wbuf + 300032))[j] = (e & 1) ? cosf(ang) : sinf(ang);
        }
    }
}

// ---------------- transformer: 2 blocks / batch element (sequence split), 8 waves each ----
// Block 2b+half owns query-row tiles TS(half, 0..7); computes K/V for ALL rows (redundant).
// Cross-block: post-LN2 x exchanged via global xg (parity slots) + flag counter (device scope).
// NOTE: plain __launch_bounds__(512) — any min-waves hint caps VGPRs at 64 and spills
// (rounds 3-8, 14). 128 VGPR + 72KB LDS => 2 blocks/CU co-resident (4 waves/SIMD).
__global__ __launch_bounds__(512)
void tf_kernel(const int* __restrict__ inp, const int* __restrict__ labels,
               const float* __restrict__ emb,
               const float* __restrict__ bq, const float* __restrict__ bk,
               const float* __restrict__ bv, const float* __restrict__ bo,
               const float* __restrict__ ln1g, const float* __restrict__ ln1b,
               const float* __restrict__ ln2g, const float* __restrict__ ln2b,
               const float* __restrict__ b1, const float* __restrict__ b2,
               const float* __restrict__ bout,
               const unsigned short* __restrict__ wbuf,
               int* __restrict__ flags, unsigned short* __restrict__ xg,
               float* __restrict__ out_logits, float* __restrict__ partials) {
    __shared__ __attribute__((aligned(16))) char smem[71712];
    unsigned short (*xb)[72]   = (unsigned short (*)[72])(smem);
    unsigned short (*q2)[24]   = (unsigned short (*)[24])(smem + 36864);
    unsigned short (*k2)[24]   = (unsigned short (*)[24])(smem + 43008);
    unsigned short (*vt)[264]  = (unsigned short (*)[264])(smem + 55296);
    unsigned short (*proj)[72] = (unsigned short (*)[72])(smem + 36864);
    unsigned short (*hbuf)[136]= (unsigned short (*)[136])(smem + 36864);
    float* red = (float*)(smem + 71680);

    const unsigned short* wqkvt = wbuf;
    const unsigned short* wot   = wbuf + 73728;
    const unsigned short* w1t   = wbuf + 98304;
    const unsigned short* w2t   = wbuf + 196608;
    const unsigned short* woutt = wbuf + 294912;
    const float* pef = (const float*)(wbuf + 300032);

    const int bp   = blockIdx.x >> 1;    // batch element
    const int half = blockIdx.x & 1;     // sequence half (interleaved tiles)
    const int tid = threadIdx.x;
    const int w = tid >> 6;              // 0..7
    const int lane = tid & 63;
    const int cc = lane & 15;
    const int gg = lane >> 4;

    const bf16x8 zf = {0, 0, 0, 0, 0, 0, 0, 0};
    const bf16x8 ones = {(short)0x3F80, (short)0x3F80, (short)0x3F80, (short)0x3F80,
                         (short)0x3F80, (short)0x3F80, (short)0x3F80, (short)0x3F80};

    // bpermute source addrs for P redistribution (constant per lane)
    const int srcA = ((gg & 1) * 32 + cc) * 4;
    const int srcB = srcA + 64;

    unsigned rr[8];   // residual, own rows: row tid>>2, cols 16*(tid&3)+0..15
    const int lr = tid >> 2, qq = tid & 3;
    const int gr = 16 * TS(half, lr >> 4) + (lr & 15);   // own global row for this thread

    // ---------- embed + positional: full 256 rows (redundant), own rows -> rr ----------
    #pragma unroll
    for (int it = 0; it < 2; ++it) {
        int r = lr + 128 * it;
        int id = inp[bp * 256 + r];
        const float4* er = (const float4*)(emb + id * 64 + 16 * qq);
        const float4* pr = (const float4*)(pef + r * 64 + 16 * qq);
        unsigned nw[8];
        #pragma unroll
        for (int j = 0; j < 4; ++j) {
            float4 ev = er[j], pv = pr[j];
            nw[2 * j]     = cvtpk(ev.x + pv.x, ev.y + pv.y);
            nw[2 * j + 1] = cvtpk(ev.z + pv.z, ev.w + pv.w);
        }
        *(uint4*)&xb[r][16 * qq]     = make_uint4(nw[0], nw[1], nw[2], nw[3]);
        *(uint4*)&xb[r][16 * qq + 8] = make_uint4(nw[4], nw[5], nw[6], nw[7]);
    }
    __syncthreads();
    {   // own rows -> rr (read back)
        uint4 a = *(const uint4*)&xb[gr][16 * qq];
        uint4 c = *(const uint4*)&xb[gr][16 * qq + 8];
        rr[0] = a.x; rr[1] = a.y; rr[2] = a.z; rr[3] = a.w;
        rr[4] = c.x; rr[5] = c.y; rr[6] = c.z; rr[7] = c.w;
    }

    // owner-pass: x = LN(rr + proj) -> rr, xb (own 128 rows; 4 threads/row)
    auto ownerLN = [&](const float* gp_, const float* bp_) {
        uint4 p0 = *(const uint4*)&proj[lr][16 * qq];
        uint4 p1 = *(const uint4*)&proj[lr][16 * qq + 8];
        unsigned pw[8] = {p0.x, p0.y, p0.z, p0.w, p1.x, p1.y, p1.z, p1.w};
        float xv[16];
        float s = 0.f, s2 = 0.f;
        #pragma unroll
        for (int j = 0; j < 8; ++j) {
            float x0 = lo2f(rr[j]) + lo2f(pw[j]);
            float x1 = hi2f(rr[j]) + hi2f(pw[j]);
            xv[2 * j] = x0; xv[2 * j + 1] = x1;
            s += x0 + x1; s2 += x0 * x0 + x1 * x1;
        }
        s  += __shfl_xor(s, 1, 64);  s  += __shfl_xor(s, 2, 64);
        s2 += __shfl_xor(s2, 1, 64); s2 += __shfl_xor(s2, 2, 64);
        float mu = s * 0.015625f;
        float var = s2 * 0.015625f - mu * mu;
        float rstd = rsqrtf(var + 1e-5f);
        const float4* gp = (const float4*)(gp_ + 16 * qq);
        const float4* bp4 = (const float4*)(bp_ + 16 * qq);
        #pragma unroll
        for (int j = 0; j < 4; ++j) {
            float4 gv = gp[j], bv2 = bp4[j];
            float n0 = (xv[4 * j]     - mu) * rstd * gv.x + bv2.x;
            float n1 = (xv[4 * j + 1] - mu) * rstd * gv.y + bv2.y;
            float n2 = (xv[4 * j + 2] - mu) * rstd * gv.z + bv2.z;
            float n3 = (xv[4 * j + 3] - mu) * rstd * gv.w + bv2.w;
            rr[2 * j]     = cvtpk(n0, n1);
            rr[2 * j + 1] = cvtpk(n2, n3);
        }
        *(uint4*)&xb[gr][16 * qq]     = make_uint4(rr[0], rr[1], rr[2], rr[3]);
        *(uint4*)&xb[gr][16 * qq + 8] = make_uint4(rr[4], rr[5], rr[6], rr[7]);
    };

    for (int l = 0; l < 6; ++l) {
        const unsigned short* Wqkv = wqkvt + l * 12288;

        // hoist A-frags: K/V m-tiles {2w, 2w+1} (all rows) + Q m-tile TS(half, w) (own)
        bf16x8 afk00 = *(const bf16x8*)&xb[16 * (2 * w)     + cc][8 * gg];
        bf16x8 afk01 = *(const bf16x8*)&xb[16 * (2 * w)     + cc][32 + 8 * gg];
        bf16x8 afk10 = *(const bf16x8*)&xb[16 * (2 * w + 1) + cc][8 * gg];
        bf16x8 afk11 = *(const bf16x8*)&xb[16 * (2 * w + 1) + cc][32 + 8 * gg];
        const int gq = TS(half, w);
        bf16x8 afq0 = *(const bf16x8*)&xb[16 * gq + cc][8 * gg];
        bf16x8 afq1 = *(const bf16x8*)&xb[16 * gq + cc][32 + 8 * gg];

        // ================= attention: 4 phases (head pairs) =================
        #pragma unroll
        for (int p = 0; p < 4; ++p) {
            if (p) __syncthreads();   // prev phase's q2/k2/vt reads done
            {   // Q for own tile (local slot w)
                const unsigned short* Wt = Wqkv;
                bf16x8 bf0 = *(const bf16x8*)&Wt[(16 * p + cc) * 64 + 8 * gg];
                bf16x8 bf1 = *(const bf16x8*)&Wt[(16 * p + cc) * 64 + 32 + 8 * gg];
                float bb = bq[l * 64 + 16 * p + cc];
                f32x4 c = {0.f, 0.f, 0.f, 0.f};
                c = MFMA16(afq0, bf0, c);
                c = MFMA16(afq1, bf1, c);
                #pragma unroll
                for (int r = 0; r < 4; ++r)
                    q2[16 * w + 4 * gg + r][cc] = f2b1((c[r] + bb) * 0.35355339059327373f);
            }
            #pragma unroll
            for (int mat = 1; mat < 3; ++mat) {   // K, V for ALL rows
                const unsigned short* Wt = Wqkv + mat * 4096;
                bf16x8 bf0 = *(const bf16x8*)&Wt[(16 * p + cc) * 64 + 8 * gg];
                bf16x8 bf1 = *(const bf16x8*)&Wt[(16 * p + cc) * 64 + 32 + 8 * gg];
                const float* bias = (mat == 1 ? bk : bv) + l * 64;
                float bb = bias[16 * p + cc];
                #pragma unroll
                for (int mi = 0; mi < 2; ++mi) {
                    int mt = 2 * w + mi;
                    f32x4 c = {0.f, 0.f, 0.f, 0.f};
                    c = MFMA16(mi ? afk10 : afk00, bf0, c);
                    c = MFMA16(mi ? afk11 : afk01, bf1, c);
                    if (mat == 1) {
                        #pragma unroll
                        for (int r = 0; r < 4; ++r)
                            k2[16 * mt + 4 * gg + r][cc] = f2b1(c[r] + bb);
                    } else {
                        uint2 pk;
                        pk.x = cvtpk(c[0] + bb, c[1] + bb);
                        pk.y = cvtpk(c[2] + bb, c[3] + bb);
                        *(uint2*)&vt[cc][16 * mt + 4 * gg] = pk;
                    }
                }
            }
            __syncthreads();   // q2/k2/vt ready

            #pragma unroll
            for (int hh = 0; hh < 2; ++hh) {
                const int h = 2 * p + hh;
                const int hoff = 8 * hh;
                int lt = (w + h) & 7;            // local q-tile slot
                int i = TS(half, lt);            // global i-tile
                bf16x8 qf = zf;
                if (gg == 0) qf = *(const bf16x8*)&q2[16 * lt + cc][hoff];
                f32x4 o = {0.f, 0.f, 0.f, 0.f};
                int full = i >> 1;
                for (int jc = 0; jc < full; ++jc) {
                    uint2 pk0, pk1;
                    {
                        bf16x8 kf = zf;
                        if (gg == 0) kf = *(const bf16x8*)&k2[16 * (2 * jc) + cc][hoff];
                        f32x4 sc = {0.f, 0.f, 0.f, 0.f};
                        sc = MFMA16(kf, qf, sc);
                        pk0.x = cvtpk(__expf(sc[0]), __expf(sc[1]));
                        pk0.y = cvtpk(__expf(sc[2]), __expf(sc[3]));
                    }
                    {
                        bf16x8 kf = zf;
                        if (gg == 0) kf = *(const bf16x8*)&k2[16 * (2 * jc + 1) + cc][hoff];
                        f32x4 sc = {0.f, 0.f, 0.f, 0.f};
                        sc = MFMA16(kf, qf, sc);
                        pk1.x = cvtpk(__expf(sc[0]), __expf(sc[1]));
                        pk1.y = cvtpk(__expf(sc[2]), __expf(sc[3]));
                    }
                    unsigned px = (gg >= 2) ? pk1.x : pk0.x;
                    unsigned py = (gg >= 2) ? pk1.y : pk0.y;
                    unsigned w0 = __builtin_amdgcn_ds_bpermute(srcA, px);
                    unsigned w1 = __builtin_amdgcn_ds_bpermute(srcA, py);
                    unsigned w2 = __builtin_amdgcn_ds_bpermute(srcB, px);
                    unsigned w3 = __builtin_amdgcn_ds_bpermute(srcB, py);
                    union { uint4 u; bf16x8 v; } pa_u;
                    pa_u.u = make_uint4(w0, w1, w2, w3);
                    bf16x8 vb;
                    if (cc < 8)       vb = *(const bf16x8*)&vt[hoff + cc][32 * jc + 8 * gg];
                    else if (cc == 8) vb = ones;
                    else              vb = zf;
                    o = MFMA16(pa_u.v, vb, o);
                }
                {   // tail chunk (diagonal)
                    int jc = full;
                    uint2 pk0 = make_uint2(0u, 0u), pk1 = make_uint2(0u, 0u);
                    {
                        int jt = 2 * jc;
                        bf16x8 kf = zf;
                        if (gg == 0) kf = *(const bf16x8*)&k2[16 * jt + cc][hoff];
                        f32x4 sc = {0.f, 0.f, 0.f, 0.f};
                        sc = MFMA16(kf, qf, sc);
                        float pv[4];
                        #pragma unroll
                        for (int r = 0; r < 4; ++r) {
                            float pp = __expf(sc[r]);
                            if (jt == i && 4 * gg + r > cc) pp = 0.f;
                            pv[r] = pp;
                        }
                        pk0.x = cvtpk(pv[0], pv[1]);
                        pk0.y = cvtpk(pv[2], pv[3]);
                    }
                    if (2 * jc + 1 <= i) {
                        int jt = 2 * jc + 1;
                        bf16x8 kf = zf;
                        if (gg == 0) kf = *(const bf16x8*)&k2[16 * jt + cc][hoff];
                        f32x4 sc = {0.f, 0.f, 0.f, 0.f};
                        sc = MFMA16(kf, qf, sc);
                        float pv[4];
                        #pragma unroll
                        for (int r = 0; r < 4; ++r) {
                            float pp = __expf(sc[r]);
                            if (jt == i && 4 * gg + r > cc) pp = 0.f;
                            pv[r] = pp;
                        }
                        pk1.x = cvtpk(pv[0], pv[1]);
                        pk1.y = cvtpk(pv[2], pv[3]);
                    }
                    unsigned px = (gg >= 2) ? pk1.x : pk0.x;
                    unsigned py = (gg >= 2) ? pk1.y : pk0.y;
                    unsigned w0 = __builtin_amdgcn_ds_bpermute(srcA, px);
                    unsigned w1 = __builtin_amdgcn_ds_bpermute(srcA, py);
                    unsigned w2 = __builtin_amdgcn_ds_bpermute(srcB, px);
                    unsigned w3 = __builtin_amdgcn_ds_bpermute(srcB, py);
                    union { uint4 u; bf16x8 v; } pa_u;
                    pa_u.u = make_uint4(w0, w1, w2, w3);
                    bf16x8 vb;
                    if (cc < 8)       vb = *(const bf16x8*)&vt[hoff + cc][32 * jc + 8 * gg];
                    else if (cc == 8) vb = ones;
                    else              vb = zf;
                    o = MFMA16(pa_u.v, vb, o);
                }
                // normalize + write O into xb (own global rows)
                #pragma unroll
                for (int r = 0; r < 4; ++r) {
                    float rs = __shfl(o[r], (lane & 48) + 8, 64);
                    float ov = o[r] * __builtin_amdgcn_rcpf(rs);
                    if (cc < 8)
                        xb[16 * i + 4 * gg + r][8 * h + cc] = f2b1(ov);
                }
            }
        }
        __syncthreads();   // attention done; C region free; O complete in xb own rows

        // ================= Wo projection (own rows) -> proj =================
        {
            const unsigned short* Wt = wot + l * 4096;
            int n = w & 3;
            bf16x8 bf0 = *(const bf16x8*)&Wt[(16 * n + cc) * 64 + 8 * gg];
            bf16x8 bf1 = *(const bf16x8*)&Wt[(16 * n + cc) * 64 + 32 + 8 * gg];
            float bb = bo[l * 64 + 16 * n + cc];
            #pragma unroll
            for (int t = 0; t < 4; ++t) {
                int lt = 4 * (w >> 2) + t;
                int gi = TS(half, lt);
                bf16x8 o0 = *(const bf16x8*)&xb[16 * gi + cc][8 * gg];
                bf16x8 o1 = *(const bf16x8*)&xb[16 * gi + cc][32 + 8 * gg];
                f32x4 c = {0.f, 0.f, 0.f, 0.f};
                c = MFMA16(o0, bf0, c);
                c = MFMA16(o1, bf1, c);
                #pragma unroll
                for (int r = 0; r < 4; ++r)
                    proj[16 * lt + 4 * gg + r][16 * n + cc] = f2b1(c[r] + bb);
            }
        }
        __syncthreads();
        ownerLN(ln1g + l * 64, ln1b + l * 64);
        __syncthreads();

        // ================= FFN (own rows; 2 chunks of 128 hidden cols) =================
        f32x4 facc[4];
        #pragma unroll
        for (int t = 0; t < 4; ++t) facc[t] = {0.f, 0.f, 0.f, 0.f};
        #pragma unroll
        for (int ch = 0; ch < 2; ++ch) {
            if (ch) __syncthreads();   // WAR on hbuf
            {   // FFN1: wave w = n-tile; own 8 row-tiles
                const unsigned short* Wt = w1t + l * 16384;
                int gcol = 128 * ch + 16 * w + cc;
                bf16x8 bf0 = *(const bf16x8*)&Wt[gcol * 64 + 8 * gg];
                bf16x8 bf1 = *(const bf16x8*)&Wt[gcol * 64 + 32 + 8 * gg];
                float bb = b1[l * 256 + gcol];
                #pragma unroll
                for (int lt = 0; lt < 8; ++lt) {
                    int gi = TS(half, lt);
                    bf16x8 x0 = *(const bf16x8*)&xb[16 * gi + cc][8 * gg];
                    bf16x8 x1 = *(const bf16x8*)&xb[16 * gi + cc][32 + 8 * gg];
                    f32x4 c = {0.f, 0.f, 0.f, 0.f};
                    c = MFMA16(x0, bf0, c);
                    c = MFMA16(x1, bf1, c);
                    #pragma unroll
                    for (int r = 0; r < 4; ++r)
                        hbuf[16 * lt + 4 * gg + r][16 * w + cc] = f2b1(fmaxf(c[r] + bb, 0.f));
                }
            }
            __syncthreads();
            {   // FFN2 accumulate
                const unsigned short* Wt = w2t + l * 16384;
                int n = w & 3;
                #pragma unroll
                for (int ks = 0; ks < 4; ++ks) {
                    bf16x8 bf0 = *(const bf16x8*)&Wt[(16 * n + cc) * 256 + 128 * ch + 32 * ks + 8 * gg];
                    #pragma unroll
                    for (int t = 0; t < 4; ++t) {
                        int lt = 4 * (w >> 2) + t;
                        bf16x8 h0 = *(const bf16x8*)&hbuf[16 * lt + cc][32 * ks + 8 * gg];
                        facc[t] = MFMA16(h0, bf0, facc[t]);
                    }
                }
            }
        }
        __syncthreads();
        {   // FFN2 epilogue -> proj
            int n = w & 3;
            float bb = b2[l * 64 + 16 * n + cc];
            #pragma unroll
            for (int t = 0; t < 4; ++t) {
                int lt = 4 * (w >> 2) + t;
                #pragma unroll
                for (int r = 0; r < 4; ++r)
                    proj[16 * lt + 4 * gg + r][16 * n + cc] = f2b1(facc[t][r] + bb);
            }
        }
        __syncthreads();
        ownerLN(ln2g + l * 64, ln2b + l * 64);
        __syncthreads();

        // ================= x exchange (layers 0..4) =================
        if (l < 5) {
            unsigned short* xs = xg + ((size_t)(bp * 2 + (l & 1)) * 256) * 64;
            *(uint4*)&xs[gr * 64 + 16 * qq]     = make_uint4(rr[0], rr[1], rr[2], rr[3]);
            *(uint4*)&xs[gr * 64 + 16 * qq + 8] = make_uint4(rr[4], rr[5], rr[6], rr[7]);
            __threadfence();
            __syncthreads();
            if (tid == 0) {
                atomicAdd(&flags[bp], 1);
                long guard = 0;
                while (atomicAdd(&flags[bp], 0) < 2 * (l + 1) && guard < 200000000L) ++guard;
            }
            __syncthreads();
            __threadfence();
            {   // pull other half's rows into xb
                int go = 16 * TS(half ^ 1, lr >> 4) + (lr & 15);
                uint4 a = *(const uint4*)&xs[go * 64 + 16 * qq];
                uint4 c = *(const uint4*)&xs[go * 64 + 16 * qq + 8];
                *(uint4*)&xb[go][16 * qq]     = a;
                *(uint4*)&xb[go][16 * qq + 8] = c;
            }
            __syncthreads();
        }
    } // layers

    // ================= logits (own rows): wave w -> tile TS(half,w), n=0..4 ============
    {
        int gi = TS(half, w);
        bf16x8 a0 = *(const bf16x8*)&xb[16 * gi + cc][8 * gg];
        bf16x8 a1 = *(const bf16x8*)&xb[16 * gi + cc][32 + 8 * gg];
        #pragma unroll
        for (int n = 0; n < 5; ++n) {
            bf16x8 bf0 = *(const bf16x8*)&woutt[(16 * n + cc) * 64 + 8 * gg];
            bf16x8 bf1 = *(const bf16x8*)&woutt[(16 * n + cc) * 64 + 32 + 8 * gg];
            f32x4 c = {0.f, 0.f, 0.f, 0.f};
            c = MFMA16(a0, bf0, c);
            c = MFMA16(a1, bf1, c);
            int col = 16 * n + cc;
            if (col < 65) {
                float bb = bout[col];
                #pragma unroll
                for (int r = 0; r < 4; ++r) {
                    int grow = 16 * gi + 4 * gg + r;
                    float v = c[r] + bb;
                    out_logits[((size_t)bp * 256 + grow) * 65 + col] = v;
                    proj[16 * w + 4 * gg + r][col] = f2b1(v);
                }
            }
        }
    }
    __syncthreads();

    // ================= loss partial (own 128 rows; 4 threads/row) =================
    {
        float sum = 0.f;
        for (int c2 = qq; c2 < 65; c2 += 4) sum += __expf(b2f(proj[lr][c2]));
        sum += __shfl_xor(sum, 1, 64);
        sum += __shfl_xor(sum, 2, 64);
        float nll = 0.f;
        if (qq == 0) {
            int lab = labels[bp * 256 + gr];
            nll = logf(sum) - b2f(proj[lr][lab]);
        }
        #pragma unroll
        for (int m = 1; m < 64; m <<= 1) nll += __shfl_xor(nll, m, 64);
        if (lane == 0) red[w] = nll;
        __syncthreads();
        if (tid == 0) {
            float s = 0.f;
            #pragma unroll
            for (int i = 0; i < 8; ++i) s += red[i];
            partials[blockIdx.x] = s;
        }
    }
}

__global__ __launch_bounds__(64)
void loss_reduce(const float* __restrict__ partials, float* __restrict__ out) {
    int t = threadIdx.x;
    float s = 0.f;
    #pragma unroll
    for (int k = 0; k < 8; ++k) s += partials[t + 64 * k];
    #pragma unroll
    for (int m = 1; m < 64; m <<= 1) s += __shfl_xor(s, m, 64);
    if (t == 0) out[0] = s * (1.f / 65536.f);
}

// ---------------- host ----------------
extern "C" void kernel_launch(void* const* d_in, const int* in_sizes, int n_in,
                              void* d_out, int out_size, void* d_ws, size_t ws_size,
                              hipStream_t stream) {
    const int*   inputs = (const int*)d_in[0];
    const int*   labels = (const int*)d_in[1];
    const float* emb  = (const float*)d_in[2];
    const float* Wq   = (const float*)d_in[3];
    const float* bq   = (const float*)d_in[4];
    const float* Wk   = (const float*)d_in[5];
    const float* bk   = (const float*)d_in[6];
    const float* Wv   = (const float*)d_in[7];
    const float* bv   = (const float*)d_in[8];
    const float* Wo   = (const float*)d_in[9];
    const float* bo   = (const float*)d_in[10];
    const float* ln1g = (const float*)d_in[11];
    const float* ln1b = (const float*)d_in[12];
    const float* ln2g = (const float*)d_in[13];
    const float* ln2b = (const float*)d_in[14];
    const float* W1   = (const float*)d_in[15];
    const float* b1   = (const float*)d_in[16];
    const float* W2   = (const float*)d_in[17];
    const float* b2   = (const float*)d_in[18];
    const float* Wout = (const float*)d_in[19];
    const float* bout = (const float*)d_in[20];

    float* logits = (float*)d_out;
    float* loss   = logits + (size_t)65536 * 65;

    float* partials = (float*)d_ws;                                   // 512 f32
    int*   flags    = (int*)((char*)d_ws + 2048);                     // 256 i32
    unsigned short* wbuf = (unsigned short*)((char*)d_ws + 4096);     // 665600 B
    unsigned short* xg   = (unsigned short*)((char*)d_ws + 670720);   // 16.8 MB

    hipMemsetAsync(flags, 0, 256 * sizeof(int), stream);   // fresh pair-barrier counters
    prep_kernel<<<dim3(192, 7), 256, 0, stream>>>(Wq, Wk, Wv, Wo, W1, W2, Wout, wbuf);
    tf_kernel<<<512, 512, 0, stream>>>(inputs, labels, emb,
                                       bq, bk, bv, bo,
                                       ln1g, ln1b, ln2g, ln2b,
                                       b1, b2, bout,
                                       wbuf, flags, xg, logits, partials);
    loss_reduce<<<1, 64, 0, stream>>>(partials, loss);
}

// Round 16
// 356.020 us; speedup vs baseline: 3.6654x; 3.5455x over previous
//
#include <hip/hip_runtime.h>
#include <math.h>

#define VOCAB 65
#define NBATCH 256

typedef __attribute__((ext_vector_type(8))) short bf16x8;
typedef __attribute__((ext_vector_type(4))) float f32x4;

#define MFMA16(a, b, c) __builtin_amdgcn_mfma_f32_16x16x32_bf16((a), (b), (c), 0, 0, 0)

__device__ __forceinline__ unsigned short f2b(float f) {
    union { float f; unsigned u; } v; v.f = f;
    unsigned r = (v.u + 0x7fffu + ((v.u >> 16) & 1u)) >> 16;
    return (unsigned short)r;
}
__device__ __forceinline__ unsigned cvtpk(float lo, float hi) {
    unsigned r; asm("v_cvt_pk_bf16_f32 %0, %1, %2" : "=v"(r) : "v"(lo), "v"(hi)); return r;
}
__device__ __forceinline__ unsigned short f2b1(float v) { return (unsigned short)cvtpk(v, v); }
__device__ __forceinline__ float b2f(unsigned short h) {
    union { unsigned u; float f; } v; v.u = ((unsigned)h) << 16; return v.f;
}
__device__ __forceinline__ float lo2f(unsigned wd) {
    union { unsigned u; float f; } v; v.u = wd << 16; return v.f;
}
__device__ __forceinline__ float hi2f(unsigned wd) {
    union { unsigned u; float f; } v; v.u = wd & 0xffff0000u; return v.f;
}

// wbuf layout (shorts): wqkvt 6*[3][64][64] @0 ; wot 6*[64][64] @73728 ;
// w1t 6*[256][64] @98304 ; w2t 6*[64][256] @196608 ; woutt [80][64] @294912 ;
// PE table (float[256][64]) @short-offset 300032
__global__ __launch_bounds__(256)
void prep_kernel(const float* __restrict__ Wq, const float* __restrict__ Wk,
                 const float* __restrict__ Wv, const float* __restrict__ Wo,
                 const float* __restrict__ W1, const float* __restrict__ W2,
                 const float* __restrict__ Wout, unsigned short* __restrict__ wbuf) {
    int l = blockIdx.y;
    int idx = blockIdx.x * 256 + threadIdx.x;
    if (l < 6) {
        float v; unsigned short* dst;
        if (idx < 12288) {                    // wqkvt [mat][m][k] = Wmat[l][k][m]
            int mat = idx >> 12, m = (idx >> 6) & 63, k = idx & 63;
            const float* W = mat == 0 ? Wq : (mat == 1 ? Wk : Wv);
            v = W[l * 4096 + k * 64 + m];
            dst = wbuf + l * 12288 + idx;
        } else if (idx < 16384) {             // wot [m][k]
            int j = idx - 12288; int m = j >> 6, k = j & 63;
            v = Wo[l * 4096 + k * 64 + m];
            dst = wbuf + 73728 + l * 4096 + j;
        } else if (idx < 32768) {             // w1t [m(256)][k(64)]
            int j = idx - 16384; int m = j >> 6, k = j & 63;
            v = W1[l * 16384 + k * 256 + m];
            dst = wbuf + 98304 + l * 16384 + j;
        } else {                              // w2t [m(64)][k(256)]
            int j = idx - 32768; int m = j >> 8, k = j & 255;
            v = W2[l * 16384 + k * 64 + m];
            dst = wbuf + 196608 + l * 16384 + j;
        }
        *dst = f2b(v);
    } else {
        if (idx < 5120) {                     // woutt [m(80)][k(64)], rows>=65 zero
            int m = idx >> 6, k = idx & 63;
            float v = (m < 65) ? Wout[k * 65 + m] : 0.f;
            wbuf[294912 + idx] = f2b(v);
        } else if (idx < 21504) {             // PE table f32 [256][64]
            int j = idx - 5120; int t = j >> 6, e = j & 63;
            int i2 = e >> 1;
            float div = expf(-(float)(2 * i2) * 0.14391156831212788f);
            float ang = (float)t * div;
            ((float*)(wbuf + 300032))[j] = (e & 1) ? cosf(ang) : sinf(ang);
        }
    }
}

// ---------------- whole transformer: 1 block / batch element, 8 waves (512 thr) ----------------
// Round-13 structure (best: 309.2us, bpermute P-path) + depth-1 software pipeline in the
// flash chunk loop: produce (pa,vb) for chunk jc+1 while PV-MFMA of chunk jc issues.
// LDS map (bytes):
//   [0,36864)      xb[256][72] : x (A-frags hoisted at layer start); O during attention
//   [36864,106496) C region, phase-overlaid:
//     attn:  q2[256][24] @36864 | k2[256][24] @49152 | vt[16][264] @61440
//     epi:   proj[256][72] @36864
//     FFN:   hb[256][136] @36864
//   [106496,106528) red[8]
__global__ __launch_bounds__(512)
void tf_kernel(const int* __restrict__ inp, const int* __restrict__ labels,
               const float* __restrict__ emb,
               const float* __restrict__ bq, const float* __restrict__ bk,
               const float* __restrict__ bv, const float* __restrict__ bo,
               const float* __restrict__ ln1g, const float* __restrict__ ln1b,
               const float* __restrict__ ln2g, const float* __restrict__ ln2b,
               const float* __restrict__ b1, const float* __restrict__ b2,
               const float* __restrict__ bout,
               const unsigned short* __restrict__ wbuf,
               float* __restrict__ out_logits, float* __restrict__ partials) {
    __shared__ __attribute__((aligned(16))) char smem[106528];
    unsigned short (*xb)[72]      = (unsigned short (*)[72])(smem);
    unsigned short (*q2)[24]      = (unsigned short (*)[24])(smem + 36864);
    unsigned short (*k2)[24]      = (unsigned short (*)[24])(smem + 49152);
    unsigned short (*vt)[264]     = (unsigned short (*)[264])(smem + 61440);
    unsigned short (*proj)[72]    = (unsigned short (*)[72])(smem + 36864);
    unsigned short (*hb)[136]     = (unsigned short (*)[136])(smem + 36864);
    float* red = (float*)(smem + 106496);

    const unsigned short* wqkvt = wbuf;
    const unsigned short* wot   = wbuf + 73728;
    const unsigned short* w1t   = wbuf + 98304;
    const unsigned short* w2t   = wbuf + 196608;
    const unsigned short* woutt = wbuf + 294912;
    const float* pef = (const float*)(wbuf + 300032);

    const int b = blockIdx.x;
    const int tid = threadIdx.x;
    const int w = tid >> 6;          // 0..7
    const int lane = tid & 63;
    const int cc = lane & 15;
    const int gg = lane >> 4;

    const bf16x8 zf = {0, 0, 0, 0, 0, 0, 0, 0};
    const bf16x8 ones = {(short)0x3F80, (short)0x3F80, (short)0x3F80, (short)0x3F80,
                         (short)0x3F80, (short)0x3F80, (short)0x3F80, (short)0x3F80};

    // bpermute source byte-addresses for the P redistribution (constant per lane)
    const int srcA = ((gg & 1) * 32 + cc) * 4;
    const int srcB = srcA + 64;

    unsigned rr[16];   // residual: row tid>>1, cols 32*(tid&1)+0..31 (16 packed bf16 pairs)
    const int lrow = tid >> 1, lq = tid & 1;

    // ---------- embed + positional (table) ----------
    {
        int id = inp[b * 256 + lrow];
        const float4* er = (const float4*)(emb + id * 64 + 32 * lq);
        const float4* pr = (const float4*)(pef + lrow * 64 + 32 * lq);
        #pragma unroll
        for (int j = 0; j < 8; ++j) {
            float4 ev = er[j], pv = pr[j];
            rr[2 * j]     = cvtpk(ev.x + pv.x, ev.y + pv.y);
            rr[2 * j + 1] = cvtpk(ev.z + pv.z, ev.w + pv.w);
        }
        #pragma unroll
        for (int j = 0; j < 4; ++j)
            *(uint4*)&xb[lrow][32 * lq + 8 * j] = make_uint4(rr[4 * j], rr[4 * j + 1], rr[4 * j + 2], rr[4 * j + 3]);
    }
    __syncthreads();

    // fused owner-pass: x = LN(rr + proj) -> rr, xb
    auto ownerLN = [&](const float* gp_, const float* bp_) {
        unsigned pw[16];
        #pragma unroll
        for (int j = 0; j < 4; ++j) {
            uint4 p = *(const uint4*)&proj[lrow][32 * lq + 8 * j];
            pw[4 * j] = p.x; pw[4 * j + 1] = p.y; pw[4 * j + 2] = p.z; pw[4 * j + 3] = p.w;
        }
        float xv[32];
        float s = 0.f, s2 = 0.f;
        #pragma unroll
        for (int j = 0; j < 16; ++j) {
            float x0 = lo2f(rr[j]) + lo2f(pw[j]);
            float x1 = hi2f(rr[j]) + hi2f(pw[j]);
            xv[2 * j] = x0; xv[2 * j + 1] = x1;
            s += x0 + x1; s2 += x0 * x0 + x1 * x1;
        }
        s  += __shfl_xor(s, 1, 64);
        s2 += __shfl_xor(s2, 1, 64);
        float mu = s * 0.015625f;
        float var = s2 * 0.015625f - mu * mu;
        float rstd = rsqrtf(var + 1e-5f);
        const float4* gp = (const float4*)(gp_ + 32 * lq);
        const float4* bp = (const float4*)(bp_ + 32 * lq);
        #pragma unroll
        for (int j = 0; j < 8; ++j) {
            float4 gv = gp[j], bv2 = bp[j];
            float n0 = (xv[4 * j]     - mu) * rstd * gv.x + bv2.x;
            float n1 = (xv[4 * j + 1] - mu) * rstd * gv.y + bv2.y;
            float n2 = (xv[4 * j + 2] - mu) * rstd * gv.z + bv2.z;
            float n3 = (xv[4 * j + 3] - mu) * rstd * gv.w + bv2.w;
            rr[2 * j]     = cvtpk(n0, n1);
            rr[2 * j + 1] = cvtpk(n2, n3);
        }
        #pragma unroll
        for (int j = 0; j < 4; ++j)
            *(uint4*)&xb[lrow][32 * lq + 8 * j] = make_uint4(rr[4 * j], rr[4 * j + 1], rr[4 * j + 2], rr[4 * j + 3]);
    };

    for (int l = 0; l < 6; ++l) {
        const unsigned short* Wqkv = wqkvt + l * 12288;

        // hoist this wave's 2 QKV A-fragments (m-tiles 2w, 2w+1); xb then free for O
        bf16x8 af00 = *(const bf16x8*)&xb[16 * (2 * w)     + cc][8 * gg];
        bf16x8 af01 = *(const bf16x8*)&xb[16 * (2 * w)     + cc][32 + 8 * gg];
        bf16x8 af10 = *(const bf16x8*)&xb[16 * (2 * w + 1) + cc][8 * gg];
        bf16x8 af11 = *(const bf16x8*)&xb[16 * (2 * w + 1) + cc][32 + 8 * gg];

        // ================= attention =================
        #pragma unroll
        for (int p = 0; p < 4; ++p) {
            __syncthreads();   // p=0: hoists done; p>0: prev pair's q2/k2/vt reads done
            #pragma unroll
            for (int mat = 0; mat < 3; ++mat) {
                const unsigned short* Wt = Wqkv + mat * 4096;
                bf16x8 bf0 = *(const bf16x8*)&Wt[(16 * p + cc) * 64 + 8 * gg];
                bf16x8 bf1 = *(const bf16x8*)&Wt[(16 * p + cc) * 64 + 32 + 8 * gg];
                const float* bias = (mat == 0 ? bq : (mat == 1 ? bk : bv)) + l * 64;
                float bb = bias[16 * p + cc];
                #pragma unroll
                for (int mi = 0; mi < 2; ++mi) {
                    int mt = 2 * w + mi;
                    f32x4 c = {0.f, 0.f, 0.f, 0.f};
                    c = MFMA16(mi ? af10 : af00, bf0, c);
                    c = MFMA16(mi ? af11 : af01, bf1, c);
                    if (mat == 0) {
                        #pragma unroll
                        for (int r = 0; r < 4; ++r)
                            q2[16 * mt + 4 * gg + r][cc] = f2b1((c[r] + bb) * 0.35355339059327373f);
                    } else if (mat == 1) {
                        #pragma unroll
                        for (int r = 0; r < 4; ++r)
                            k2[16 * mt + 4 * gg + r][cc] = f2b1(c[r] + bb);
                    } else {
                        uint2 pk;
                        pk.x = cvtpk(c[0] + bb, c[1] + bb);
                        pk.y = cvtpk(c[2] + bb, c[3] + bb);
                        *(uint2*)&vt[cc][16 * mt + 4 * gg] = pk;   // [d][key]
                    }
                }
            }
            __syncthreads();   // q2/k2/vt ready

            #pragma unroll
            for (int hh = 0; hh < 2; ++hh) {
                const int h = 2 * p + hh;
                const int hoff = 8 * hh;
                int a_ = (w + h) & 7;
                #pragma unroll
                for (int s = 0; s < 2; ++s) {
                    int i = s ? (15 - a_) : a_;
                    bf16x8 qf = zf;
                    if (gg == 0) qf = *(const bf16x8*)&q2[16 * i + cc][hoff];
                    f32x4 o = {0.f, 0.f, 0.f, 0.f};
                    const int full = i >> 1;

                    // fast producer (no masking): chunk jc < full
                    auto prodF = [&](int jc) -> bf16x8 {
                        uint2 pk0, pk1;
                        {
                            bf16x8 kf = zf;
                            if (gg == 0) kf = *(const bf16x8*)&k2[16 * (2 * jc) + cc][hoff];
                            f32x4 sc = {0.f, 0.f, 0.f, 0.f};
                            sc = MFMA16(kf, qf, sc);   // row=key 4gg+r, col=query cc
                            pk0.x = cvtpk(__expf(sc[0]), __expf(sc[1]));
                            pk0.y = cvtpk(__expf(sc[2]), __expf(sc[3]));
                        }
                        {
                            bf16x8 kf = zf;
                            if (gg == 0) kf = *(const bf16x8*)&k2[16 * (2 * jc + 1) + cc][hoff];
                            f32x4 sc = {0.f, 0.f, 0.f, 0.f};
                            sc = MFMA16(kf, qf, sc);
                            pk1.x = cvtpk(__expf(sc[0]), __expf(sc[1]));
                            pk1.y = cvtpk(__expf(sc[2]), __expf(sc[3]));
                        }
                        unsigned px = (gg >= 2) ? pk1.x : pk0.x;
                        unsigned py = (gg >= 2) ? pk1.y : pk0.y;
                        union { uint4 u; bf16x8 v; } pa_u;
                        pa_u.u = make_uint4(__builtin_amdgcn_ds_bpermute(srcA, px),
                                            __builtin_amdgcn_ds_bpermute(srcA, py),
                                            __builtin_amdgcn_ds_bpermute(srcB, px),
                                            __builtin_amdgcn_ds_bpermute(srcB, py));
                        return pa_u.v;
                    };
                    // tail producer (diagonal masking): chunk jc == full
                    auto prodT = [&](int jc) -> bf16x8 {
                        uint2 pk0 = make_uint2(0u, 0u), pk1 = make_uint2(0u, 0u);
                        {
                            int jt = 2 * jc;
                            bf16x8 kf = zf;
                            if (gg == 0) kf = *(const bf16x8*)&k2[16 * jt + cc][hoff];
                            f32x4 sc = {0.f, 0.f, 0.f, 0.f};
                            sc = MFMA16(kf, qf, sc);
                            float pv[4];
                            #pragma unroll
                            for (int r = 0; r < 4; ++r) {
                                float pp = __expf(sc[r]);
                                if (jt == i && 4 * gg + r > cc) pp = 0.f;   // causal diag
                                pv[r] = pp;
                            }
                            pk0.x = cvtpk(pv[0], pv[1]);
                            pk0.y = cvtpk(pv[2], pv[3]);
                        }
                        if (2 * jc + 1 <= i) {   // wave-uniform
                            int jt = 2 * jc + 1;
                            bf16x8 kf = zf;
                            if (gg == 0) kf = *(const bf16x8*)&k2[16 * jt + cc][hoff];
                            f32x4 sc = {0.f, 0.f, 0.f, 0.f};
                            sc = MFMA16(kf, qf, sc);
                            float pv[4];
                            #pragma unroll
                            for (int r = 0; r < 4; ++r) {
                                float pp = __expf(sc[r]);
                                if (jt == i && 4 * gg + r > cc) pp = 0.f;
                                pv[r] = pp;
                            }
                            pk1.x = cvtpk(pv[0], pv[1]);
                            pk1.y = cvtpk(pv[2], pv[3]);
                        }
                        unsigned px = (gg >= 2) ? pk1.x : pk0.x;
                        unsigned py = (gg >= 2) ? pk1.y : pk0.y;
                        union { uint4 u; bf16x8 v; } pa_u;
                        pa_u.u = make_uint4(__builtin_amdgcn_ds_bpermute(srcA, px),
                                            __builtin_amdgcn_ds_bpermute(srcA, py),
                                            __builtin_amdgcn_ds_bpermute(srcB, px),
                                            __builtin_amdgcn_ds_bpermute(srcB, py));
                        return pa_u.v;
                    };
                    auto vld = [&](int jc) -> bf16x8 {
                        bf16x8 vb;
                        if (cc < 8)       vb = *(const bf16x8*)&vt[hoff + cc][32 * jc + 8 * gg];
                        else if (cc == 8) vb = ones;   // rowsum column
                        else              vb = zf;
                        return vb;
                    };

                    // depth-1 software pipeline: produce chunk jc+1 while consuming jc
                    bf16x8 pa = (full == 0) ? prodT(0) : prodF(0);
                    bf16x8 vb = vld(0);
                    for (int jc = 0; jc <= full; ++jc) {
                        bf16x8 pan = pa, vbn = vb;
                        if (jc + 1 < full)        { pan = prodF(jc + 1); vbn = vld(jc + 1); }
                        else if (jc + 1 == full)  { pan = prodT(jc + 1); vbn = vld(jc + 1); }
                        o = MFMA16(pa, vb, o);
                        pa = pan; vb = vbn;
                    }

                    // normalize + write O straight into xb
                    #pragma unroll
                    for (int r = 0; r < 4; ++r) {
                        float rs = __shfl(o[r], (lane & 48) + 8, 64);
                        float ov = o[r] * __builtin_amdgcn_rcpf(rs);
                        if (cc < 8)
                            xb[16 * i + 4 * gg + r][8 * h + cc] = f2b1(ov);
                    }
                }
            }
        }
        __syncthreads();   // attention done; q2/k2/vt dead; O complete in xb

        // ================= Wo projection -> proj =================
        {
            const unsigned short* Wt = wot + l * 4096;
            int n = w & 3;
            bf16x8 bf0 = *(const bf16x8*)&Wt[(16 * n + cc) * 64 + 8 * gg];
            bf16x8 bf1 = *(const bf16x8*)&Wt[(16 * n + cc) * 64 + 32 + 8 * gg];
            float bb = bo[l * 64 + 16 * n + cc];
            #pragma unroll
            for (int mi = 0; mi < 8; ++mi) {
                int mt = 8 * (w >> 2) + mi;
                bf16x8 o0 = *(const bf16x8*)&xb[16 * mt + cc][8 * gg];
                bf16x8 o1 = *(const bf16x8*)&xb[16 * mt + cc][32 + 8 * gg];
                f32x4 c = {0.f, 0.f, 0.f, 0.f};
                c = MFMA16(o0, bf0, c);
                c = MFMA16(o1, bf1, c);
                #pragma unroll
                for (int r = 0; r < 4; ++r)
                    proj[16 * mt + 4 * gg + r][16 * n + cc] = f2b1(c[r] + bb);
            }
        }
        __syncthreads();
        ownerLN(ln1g + l * 64, ln1b + l * 64);   // x = LN(rr + proj) -> rr, xb
        __syncthreads();

        // ================= FFN (2 chunks of 128 hidden cols) =================
        f32x4 facc[8];
        #pragma unroll
        for (int t = 0; t < 8; ++t) facc[t] = {0.f, 0.f, 0.f, 0.f};
        #pragma unroll
        for (int ch = 0; ch < 2; ++ch) {
            if (ch) __syncthreads();   // WAR on hb
            {   // FFN1 -> hb (relu): wave w = n-tile, all 16 m-tiles
                const unsigned short* Wt = w1t + l * 16384;
                int gcol = 128 * ch + 16 * w + cc;
                bf16x8 bf0 = *(const bf16x8*)&Wt[gcol * 64 + 8 * gg];
                bf16x8 bf1 = *(const bf16x8*)&Wt[gcol * 64 + 32 + 8 * gg];
                float bb = b1[l * 256 + gcol];
                #pragma unroll
                for (int mt = 0; mt < 16; ++mt) {
                    bf16x8 x0 = *(const bf16x8*)&xb[16 * mt + cc][8 * gg];
                    bf16x8 x1 = *(const bf16x8*)&xb[16 * mt + cc][32 + 8 * gg];
                    f32x4 c = {0.f, 0.f, 0.f, 0.f};
                    c = MFMA16(x0, bf0, c);
                    c = MFMA16(x1, bf1, c);
                    #pragma unroll
                    for (int r = 0; r < 4; ++r)
                        hb[16 * mt + 4 * gg + r][16 * w + cc] = f2b1(fmaxf(c[r] + bb, 0.f));
                }
            }
            __syncthreads();
            {   // FFN2 accumulate
                const unsigned short* Wt = w2t + l * 16384;
                int n = w & 3;
                #pragma unroll
                for (int ks = 0; ks < 4; ++ks) {
                    bf16x8 bf0 = *(const bf16x8*)&Wt[(16 * n + cc) * 256 + 128 * ch + 32 * ks + 8 * gg];
                    #pragma unroll
                    for (int mi = 0; mi < 8; ++mi) {
                        int mt = 8 * (w >> 2) + mi;
                        bf16x8 h0 = *(const bf16x8*)&hb[16 * mt + cc][32 * ks + 8 * gg];
                        facc[mi] = MFMA16(h0, bf0, facc[mi]);
                    }
                }
            }
        }
        __syncthreads();   // last hb reads done (hb aliases proj)
        {   // FFN2 epilogue -> proj
            int n = w & 3;
            float bb = b2[l * 64 + 16 * n + cc];
            #pragma unroll
            for (int mi = 0; mi < 8; ++mi) {
                int mt = 8 * (w >> 2) + mi;
                #pragma unroll
                for (int r = 0; r < 4; ++r)
                    proj[16 * mt + 4 * gg + r][16 * n + cc] = f2b1(facc[mi][r] + bb);
            }
        }
        __syncthreads();
        ownerLN(ln2g + l * 64, ln2b + l * 64);   // x = LN(rr + proj) -> rr, xb
        __syncthreads();
    } // layers

    // ================= logits (80 tiles = 16 m x 5 n; 10 per wave) =================
    #pragma unroll
    for (int t = 0; t < 10; ++t) {
        int id = w + 8 * t;             // 0..79
        int n = id >> 4, mt = id & 15;
        bf16x8 a0 = *(const bf16x8*)&xb[16 * mt + cc][8 * gg];
        bf16x8 a1 = *(const bf16x8*)&xb[16 * mt + cc][32 + 8 * gg];
        bf16x8 bf0 = *(const bf16x8*)&woutt[(16 * n + cc) * 64 + 8 * gg];
        bf16x8 bf1 = *(const bf16x8*)&woutt[(16 * n + cc) * 64 + 32 + 8 * gg];
        f32x4 c = {0.f, 0.f, 0.f, 0.f};
        c = MFMA16(a0, bf0, c);
        c = MFMA16(a1, bf1, c);
        int col = 16 * n + cc;
        if (col < 65) {
            float bb = bout[col];
            #pragma unroll
            for (int r = 0; r < 4; ++r) {
                int row = 16 * mt + 4 * gg + r;
                float v = c[r] + bb;
                out_logits[((size_t)b * 256 + row) * 65 + col] = v;
                proj[row][col] = f2b1(v);   // stage for loss
            }
        }
    }
    __syncthreads();

    // ================= loss partial =================
    {
        float sum = 0.f;
        for (int c2 = lq; c2 < 65; c2 += 2) sum += __expf(b2f(proj[lrow][c2]));
        sum += __shfl_xor(sum, 1, 64);
        float nll = 0.f;
        if (lq == 0) {
            int lab = labels[b * 256 + lrow];
            nll = logf(sum) - b2f(proj[lrow][lab]);
        }
        #pragma unroll
        for (int m = 1; m < 64; m <<= 1) nll += __shfl_xor(nll, m, 64);
        if (lane == 0) red[w] = nll;
        __syncthreads();
        if (tid == 0) {
            float s = 0.f;
            #pragma unroll
            for (int i = 0; i < 8; ++i) s += red[i];
            partials[b] = s;
        }
    }
}

__global__ __launch_bounds__(64)
void loss_reduce(const float* __restrict__ partials, float* __restrict__ out) {
    int t = threadIdx.x;
    float s = partials[t] + partials[t + 64] + partials[t + 128] + partials[t + 192];
    #pragma unroll
    for (int m = 1; m < 64; m <<= 1) s += __shfl_xor(s, m, 64);
    if (t == 0) out[0] = s * (1.f / 65536.f);
}

// ---------------- host ----------------
extern "C" void kernel_launch(void* const* d_in, const int* in_sizes, int n_in,
                              void* d_out, int out_size, void* d_ws, size_t ws_size,
                              hipStream_t stream) {
    const int*   inputs = (const int*)d_in[0];
    const int*   labels = (const int*)d_in[1];
    const float* emb  = (const float*)d_in[2];
    const float* Wq   = (const float*)d_in[3];
    const float* bq   = (const float*)d_in[4];
    const float* Wk   = (const float*)d_in[5];
    const float* bk   = (const float*)d_in[6];
    const float* Wv   = (const float*)d_in[7];
    const float* bv   = (const float*)d_in[8];
    const float* Wo   = (const float*)d_in[9];
    const float* bo   = (const float*)d_in[10];
    const float* ln1g = (const float*)d_in[11];
    const float* ln1b = (const float*)d_in[12];
    const float* ln2g = (const float*)d_in[13];
    const float* ln2b = (const float*)d_in[14];
    const float* W1   = (const float*)d_in[15];
    const float* b1   = (const float*)d_in[16];
    const float* W2   = (const float*)d_in[17];
    const float* b2   = (const float*)d_in[18];
    const float* Wout = (const float*)d_in[19];
    const float* bout = (const float*)d_in[20];

    float* logits = (float*)d_out;
    float* loss   = logits + (size_t)65536 * 65;

    float* partials = (float*)d_ws;
    unsigned short* wbuf = (unsigned short*)((char*)d_ws + 1024);

    prep_kernel<<<dim3(192, 7), 256, 0, stream>>>(Wq, Wk, Wv, Wo, W1, W2, Wout, wbuf);
    tf_kernel<<<NBATCH, 512, 0, stream>>>(inputs, labels, emb,
                                          bq, bk, bv, bo,
                                          ln1g, ln1b, ln2g, ln2b,
                                          b1, b2, bout,
                                          wbuf, logits, partials);
    loss_reduce<<<1, 64, 0, stream>>>(partials, loss);
}

// Round 17
// 308.686 us; speedup vs baseline: 4.2274x; 1.1533x over previous
//
#include <hip/hip_runtime.h>
#include <math.h>

#define VOCAB 65
#define NBATCH 256

typedef __attribute__((ext_vector_type(8))) short bf16x8;
typedef __attribute__((ext_vector_type(4))) float f32x4;

#define MFMA16(a, b, c) __builtin_amdgcn_mfma_f32_16x16x32_bf16((a), (b), (c), 0, 0, 0)

__device__ __forceinline__ unsigned short f2b(float f) {
    union { float f; unsigned u; } v; v.f = f;
    unsigned r = (v.u + 0x7fffu + ((v.u >> 16) & 1u)) >> 16;
    return (unsigned short)r;
}
__device__ __forceinline__ unsigned cvtpk(float lo, float hi) {
    unsigned r; asm("v_cvt_pk_bf16_f32 %0, %1, %2" : "=v"(r) : "v"(lo), "v"(hi)); return r;
}
__device__ __forceinline__ unsigned short f2b1(float v) { return (unsigned short)cvtpk(v, v); }
__device__ __forceinline__ float b2f(unsigned short h) {
    union { unsigned u; float f; } v; v.u = ((unsigned)h) << 16; return v.f;
}
__device__ __forceinline__ float lo2f(unsigned wd) {
    union { unsigned u; float f; } v; v.u = wd << 16; return v.f;
}
__device__ __forceinline__ float hi2f(unsigned wd) {
    union { unsigned u; float f; } v; v.u = wd & 0xffff0000u; return v.f;
}

// wbuf layout (shorts): wqkvt 6*[3][64][64] @0 ; wot 6*[64][64] @73728 ;
// w1t 6*[256][64] @98304 ; w2t 6*[64][256] @196608 ; woutt [80][64] @294912 ;
// PE table (float[256][64]) @short-offset 300032
__global__ __launch_bounds__(256)
void prep_kernel(const float* __restrict__ Wq, const float* __restrict__ Wk,
                 const float* __restrict__ Wv, const float* __restrict__ Wo,
                 const float* __restrict__ W1, const float* __restrict__ W2,
                 const float* __restrict__ Wout, unsigned short* __restrict__ wbuf) {
    int l = blockIdx.y;
    int idx = blockIdx.x * 256 + threadIdx.x;
    if (l < 6) {
        float v; unsigned short* dst;
        if (idx < 12288) {                    // wqkvt [mat][m][k] = Wmat[l][k][m]
            int mat = idx >> 12, m = (idx >> 6) & 63, k = idx & 63;
            const float* W = mat == 0 ? Wq : (mat == 1 ? Wk : Wv);
            v = W[l * 4096 + k * 64 + m];
            dst = wbuf + l * 12288 + idx;
        } else if (idx < 16384) {             // wot [m][k]
            int j = idx - 12288; int m = j >> 6, k = j & 63;
            v = Wo[l * 4096 + k * 64 + m];
            dst = wbuf + 73728 + l * 4096 + j;
        } else if (idx < 32768) {             // w1t [m(256)][k(64)]
            int j = idx - 16384; int m = j >> 6, k = j & 63;
            v = W1[l * 16384 + k * 256 + m];
            dst = wbuf + 98304 + l * 16384 + j;
        } else {                              // w2t [m(64)][k(256)]
            int j = idx - 32768; int m = j >> 8, k = j & 255;
            v = W2[l * 16384 + k * 64 + m];
            dst = wbuf + 196608 + l * 16384 + j;
        }
        *dst = f2b(v);
    } else {
        if (idx < 5120) {                     // woutt [m(80)][k(64)], rows>=65 zero
            int m = idx >> 6, k = idx & 63;
            float v = (m < 65) ? Wout[k * 65 + m] : 0.f;
            wbuf[294912 + idx] = f2b(v);
        } else if (idx < 21504) {             // PE table f32 [256][64]
            int j = idx - 5120; int t = j >> 6, e = j & 63;
            int i2 = e >> 1;
            float div = expf(-(float)(2 * i2) * 0.14391156831212788f);
            float ang = (float)t * div;
            ((float*)(wbuf + 300032))[j] = (e & 1) ? cosf(ang) : sinf(ang);
        }
    }
}

// ---------------- whole transformer: 1 block / batch element, 8 waves (512 thr) ----------------
// Round-13 structure (champion: 309.2us, bpermute P-path) + s_setprio(1) around the flash
// inner loop (T5: waves drift between barriers due to different task lengths -> role split).
// LDS map (bytes):
//   [0,36864)      xb[256][72] : x (A-frags hoisted at layer start); O during attention
//   [36864,106496) C region, phase-overlaid:
//     attn:  q2[256][24] @36864 | k2[256][24] @49152 | vt[16][264] @61440
//     epi:   proj[256][72] @36864
//     FFN:   hb[256][136] @36864
//   [106496,106528) red[8]
__global__ __launch_bounds__(512)
void tf_kernel(const int* __restrict__ inp, const int* __restrict__ labels,
               const float* __restrict__ emb,
               const float* __restrict__ bq, const float* __restrict__ bk,
               const float* __restrict__ bv, const float* __restrict__ bo,
               const float* __restrict__ ln1g, const float* __restrict__ ln1b,
               const float* __restrict__ ln2g, const float* __restrict__ ln2b,
               const float* __restrict__ b1, const float* __restrict__ b2,
               const float* __restrict__ bout,
               const unsigned short* __restrict__ wbuf,
               float* __restrict__ out_logits, float* __restrict__ partials) {
    __shared__ __attribute__((aligned(16))) char smem[106528];
    unsigned short (*xb)[72]      = (unsigned short (*)[72])(smem);
    unsigned short (*q2)[24]      = (unsigned short (*)[24])(smem + 36864);
    unsigned short (*k2)[24]      = (unsigned short (*)[24])(smem + 49152);
    unsigned short (*vt)[264]     = (unsigned short (*)[264])(smem + 61440);
    unsigned short (*proj)[72]    = (unsigned short (*)[72])(smem + 36864);
    unsigned short (*hb)[136]     = (unsigned short (*)[136])(smem + 36864);
    float* red = (float*)(smem + 106496);

    const unsigned short* wqkvt = wbuf;
    const unsigned short* wot   = wbuf + 73728;
    const unsigned short* w1t   = wbuf + 98304;
    const unsigned short* w2t   = wbuf + 196608;
    const unsigned short* woutt = wbuf + 294912;
    const float* pef = (const float*)(wbuf + 300032);

    const int b = blockIdx.x;
    const int tid = threadIdx.x;
    const int w = tid >> 6;          // 0..7
    const int lane = tid & 63;
    const int cc = lane & 15;
    const int gg = lane >> 4;

    const bf16x8 zf = {0, 0, 0, 0, 0, 0, 0, 0};
    const bf16x8 ones = {(short)0x3F80, (short)0x3F80, (short)0x3F80, (short)0x3F80,
                         (short)0x3F80, (short)0x3F80, (short)0x3F80, (short)0x3F80};

    // bpermute source byte-addresses for the P redistribution (constant per lane):
    //   target lane (gg,cc) takes pk.x/pk.y of lanes 32*(gg&1)+cc and +16,
    //   choosing jt2=0's pack (gg<2) or jt2=1's (gg>=2).
    const int srcA = ((gg & 1) * 32 + cc) * 4;
    const int srcB = srcA + 64;

    unsigned rr[16];   // residual: row tid>>1, cols 32*(tid&1)+0..31 (16 packed bf16 pairs)
    const int lrow = tid >> 1, lq = tid & 1;

    // ---------- embed + positional (table) ----------
    {
        int id = inp[b * 256 + lrow];
        const float4* er = (const float4*)(emb + id * 64 + 32 * lq);
        const float4* pr = (const float4*)(pef + lrow * 64 + 32 * lq);
        #pragma unroll
        for (int j = 0; j < 8; ++j) {
            float4 ev = er[j], pv = pr[j];
            rr[2 * j]     = cvtpk(ev.x + pv.x, ev.y + pv.y);
            rr[2 * j + 1] = cvtpk(ev.z + pv.z, ev.w + pv.w);
        }
        #pragma unroll
        for (int j = 0; j < 4; ++j)
            *(uint4*)&xb[lrow][32 * lq + 8 * j] = make_uint4(rr[4 * j], rr[4 * j + 1], rr[4 * j + 2], rr[4 * j + 3]);
    }
    __syncthreads();

    // fused owner-pass: x = LN(rr + proj) -> rr, xb
    auto ownerLN = [&](const float* gp_, const float* bp_) {
        unsigned pw[16];
        #pragma unroll
        for (int j = 0; j < 4; ++j) {
            uint4 p = *(const uint4*)&proj[lrow][32 * lq + 8 * j];
            pw[4 * j] = p.x; pw[4 * j + 1] = p.y; pw[4 * j + 2] = p.z; pw[4 * j + 3] = p.w;
        }
        float xv[32];
        float s = 0.f, s2 = 0.f;
        #pragma unroll
        for (int j = 0; j < 16; ++j) {
            float x0 = lo2f(rr[j]) + lo2f(pw[j]);
            float x1 = hi2f(rr[j]) + hi2f(pw[j]);
            xv[2 * j] = x0; xv[2 * j + 1] = x1;
            s += x0 + x1; s2 += x0 * x0 + x1 * x1;
        }
        s  += __shfl_xor(s, 1, 64);
        s2 += __shfl_xor(s2, 1, 64);
        float mu = s * 0.015625f;
        float var = s2 * 0.015625f - mu * mu;
        float rstd = rsqrtf(var + 1e-5f);
        const float4* gp = (const float4*)(gp_ + 32 * lq);
        const float4* bp = (const float4*)(bp_ + 32 * lq);
        #pragma unroll
        for (int j = 0; j < 8; ++j) {
            float4 gv = gp[j], bv2 = bp[j];
            float n0 = (xv[4 * j]     - mu) * rstd * gv.x + bv2.x;
            float n1 = (xv[4 * j + 1] - mu) * rstd * gv.y + bv2.y;
            float n2 = (xv[4 * j + 2] - mu) * rstd * gv.z + bv2.z;
            float n3 = (xv[4 * j + 3] - mu) * rstd * gv.w + bv2.w;
            rr[2 * j]     = cvtpk(n0, n1);
            rr[2 * j + 1] = cvtpk(n2, n3);
        }
        #pragma unroll
        for (int j = 0; j < 4; ++j)
            *(uint4*)&xb[lrow][32 * lq + 8 * j] = make_uint4(rr[4 * j], rr[4 * j + 1], rr[4 * j + 2], rr[4 * j + 3]);
    };

    for (int l = 0; l < 6; ++l) {
        const unsigned short* Wqkv = wqkvt + l * 12288;

        // hoist this wave's 2 QKV A-fragments (m-tiles 2w, 2w+1); xb then free for O
        bf16x8 af00 = *(const bf16x8*)&xb[16 * (2 * w)     + cc][8 * gg];
        bf16x8 af01 = *(const bf16x8*)&xb[16 * (2 * w)     + cc][32 + 8 * gg];
        bf16x8 af10 = *(const bf16x8*)&xb[16 * (2 * w + 1) + cc][8 * gg];
        bf16x8 af11 = *(const bf16x8*)&xb[16 * (2 * w + 1) + cc][32 + 8 * gg];

        // ================= attention =================
        #pragma unroll
        for (int p = 0; p < 4; ++p) {
            __syncthreads();   // p=0: hoists done; p>0: prev pair's q2/k2/vt reads done
            #pragma unroll
            for (int mat = 0; mat < 3; ++mat) {
                const unsigned short* Wt = Wqkv + mat * 4096;
                bf16x8 bf0 = *(const bf16x8*)&Wt[(16 * p + cc) * 64 + 8 * gg];
                bf16x8 bf1 = *(const bf16x8*)&Wt[(16 * p + cc) * 64 + 32 + 8 * gg];
                const float* bias = (mat == 0 ? bq : (mat == 1 ? bk : bv)) + l * 64;
                float bb = bias[16 * p + cc];
                #pragma unroll
                for (int mi = 0; mi < 2; ++mi) {
                    int mt = 2 * w + mi;
                    f32x4 c = {0.f, 0.f, 0.f, 0.f};
                    c = MFMA16(mi ? af10 : af00, bf0, c);
                    c = MFMA16(mi ? af11 : af01, bf1, c);
                    if (mat == 0) {
                        #pragma unroll
                        for (int r = 0; r < 4; ++r)
                            q2[16 * mt + 4 * gg + r][cc] = f2b1((c[r] + bb) * 0.35355339059327373f);
                    } else if (mat == 1) {
                        #pragma unroll
                        for (int r = 0; r < 4; ++r)
                            k2[16 * mt + 4 * gg + r][cc] = f2b1(c[r] + bb);
                    } else {
                        uint2 pk;
                        pk.x = cvtpk(c[0] + bb, c[1] + bb);
                        pk.y = cvtpk(c[2] + bb, c[3] + bb);
                        *(uint2*)&vt[cc][16 * mt + 4 * gg] = pk;   // [d][key]
                    }
                }
            }
            __syncthreads();   // q2/k2/vt ready

            #pragma unroll
            for (int hh = 0; hh < 2; ++hh) {
                const int h = 2 * p + hh;
                const int hoff = 8 * hh;
                int a_ = (w + h) & 7;
                #pragma unroll
                for (int s = 0; s < 2; ++s) {
                    int i = s ? (15 - a_) : a_;
                    bf16x8 qf = zf;
                    if (gg == 0) qf = *(const bf16x8*)&q2[16 * i + cc][hoff];
                    f32x4 o = {0.f, 0.f, 0.f, 0.f};
                    int full = i >> 1;
                    __builtin_amdgcn_s_setprio(1);   // T5: favor this wave through the flash chain
                    for (int jc = 0; jc < full; ++jc) {
                        // two independent QK tiles -> packed P in regs
                        uint2 pk0, pk1;
                        {
                            bf16x8 kf = zf;
                            if (gg == 0) kf = *(const bf16x8*)&k2[16 * (2 * jc) + cc][hoff];
                            f32x4 sc = {0.f, 0.f, 0.f, 0.f};
                            sc = MFMA16(kf, qf, sc);   // row=key 4gg+r, col=query cc
                            pk0.x = cvtpk(__expf(sc[0]), __expf(sc[1]));
                            pk0.y = cvtpk(__expf(sc[2]), __expf(sc[3]));
                        }
                        {
                            bf16x8 kf = zf;
                            if (gg == 0) kf = *(const bf16x8*)&k2[16 * (2 * jc + 1) + cc][hoff];
                            f32x4 sc = {0.f, 0.f, 0.f, 0.f};
                            sc = MFMA16(kf, qf, sc);
                            pk1.x = cvtpk(__expf(sc[0]), __expf(sc[1]));
                            pk1.y = cvtpk(__expf(sc[2]), __expf(sc[3]));
                        }
                        // P redistribution: 4 bpermutes, no LDS buffer
                        unsigned px = (gg >= 2) ? pk1.x : pk0.x;
                        unsigned py = (gg >= 2) ? pk1.y : pk0.y;
                        unsigned w0 = __builtin_amdgcn_ds_bpermute(srcA, px);
                        unsigned w1 = __builtin_amdgcn_ds_bpermute(srcA, py);
                        unsigned w2 = __builtin_amdgcn_ds_bpermute(srcB, px);
                        unsigned w3 = __builtin_amdgcn_ds_bpermute(srcB, py);
                        union { uint4 u; bf16x8 v; } pa_u;
                        pa_u.u = make_uint4(w0, w1, w2, w3);
                        bf16x8 vb;
                        if (cc < 8)       vb = *(const bf16x8*)&vt[hoff + cc][32 * jc + 8 * gg];
                        else if (cc == 8) vb = ones;   // rowsum column
                        else              vb = zf;
                        o = MFMA16(pa_u.v, vb, o);
                    }
                    {   // tail chunk (diagonal)
                        int jc = full;
                        uint2 pk0 = make_uint2(0u, 0u), pk1 = make_uint2(0u, 0u);
                        {   // jt = 2*full (may be == i)
                            int jt = 2 * jc;
                            bf16x8 kf = zf;
                            if (gg == 0) kf = *(const bf16x8*)&k2[16 * jt + cc][hoff];
                            f32x4 sc = {0.f, 0.f, 0.f, 0.f};
                            sc = MFMA16(kf, qf, sc);
                            float pv[4];
                            #pragma unroll
                            for (int r = 0; r < 4; ++r) {
                                float pp = __expf(sc[r]);
                                if (jt == i && 4 * gg + r > cc) pp = 0.f;   // causal diag
                                pv[r] = pp;
                            }
                            pk0.x = cvtpk(pv[0], pv[1]);
                            pk0.y = cvtpk(pv[2], pv[3]);
                        }
                        if (2 * jc + 1 <= i) {   // wave-uniform
                            int jt = 2 * jc + 1;
                            bf16x8 kf = zf;
                            if (gg == 0) kf = *(const bf16x8*)&k2[16 * jt + cc][hoff];
                            f32x4 sc = {0.f, 0.f, 0.f, 0.f};
                            sc = MFMA16(kf, qf, sc);
                            float pv[4];
                            #pragma unroll
                            for (int r = 0; r < 4; ++r) {
                                float pp = __expf(sc[r]);
                                if (jt == i && 4 * gg + r > cc) pp = 0.f;
                                pv[r] = pp;
                            }
                            pk1.x = cvtpk(pv[0], pv[1]);
                            pk1.y = cvtpk(pv[2], pv[3]);
                        }
                        unsigned px = (gg >= 2) ? pk1.x : pk0.x;
                        unsigned py = (gg >= 2) ? pk1.y : pk0.y;
                        unsigned w0 = __builtin_amdgcn_ds_bpermute(srcA, px);
                        unsigned w1 = __builtin_amdgcn_ds_bpermute(srcA, py);
                        unsigned w2 = __builtin_amdgcn_ds_bpermute(srcB, px);
                        unsigned w3 = __builtin_amdgcn_ds_bpermute(srcB, py);
                        union { uint4 u; bf16x8 v; } pa_u;
                        pa_u.u = make_uint4(w0, w1, w2, w3);
                        bf16x8 vb;
                        if (cc < 8)       vb = *(const bf16x8*)&vt[hoff + cc][32 * jc + 8 * gg];
                        else if (cc == 8) vb = ones;
                        else              vb = zf;
                        o = MFMA16(pa_u.v, vb, o);
                    }
                    __builtin_amdgcn_s_setprio(0);
                    // normalize + write O straight into xb
                    #pragma unroll
                    for (int r = 0; r < 4; ++r) {
                        float rs = __shfl(o[r], (lane & 48) + 8, 64);
                        float ov = o[r] * __builtin_amdgcn_rcpf(rs);
                        if (cc < 8)
                            xb[16 * i + 4 * gg + r][8 * h + cc] = f2b1(ov);
                    }
                }
            }
        }
        __syncthreads();   // attention done; q2/k2/vt dead; O complete in xb

        // ================= Wo projection -> proj =================
        {
            const unsigned short* Wt = wot + l * 4096;
            int n = w & 3;
            bf16x8 bf0 = *(const bf16x8*)&Wt[(16 * n + cc) * 64 + 8 * gg];
            bf16x8 bf1 = *(const bf16x8*)&Wt[(16 * n + cc) * 64 + 32 + 8 * gg];
            float bb = bo[l * 64 + 16 * n + cc];
            #pragma unroll
            for (int mi = 0; mi < 8; ++mi) {
                int mt = 8 * (w >> 2) + mi;
                bf16x8 o0 = *(const bf16x8*)&xb[16 * mt + cc][8 * gg];
                bf16x8 o1 = *(const bf16x8*)&xb[16 * mt + cc][32 + 8 * gg];
                f32x4 c = {0.f, 0.f, 0.f, 0.f};
                c = MFMA16(o0, bf0, c);
                c = MFMA16(o1, bf1, c);
                #pragma unroll
                for (int r = 0; r < 4; ++r)
                    proj[16 * mt + 4 * gg + r][16 * n + cc] = f2b1(c[r] + bb);
            }
        }
        __syncthreads();
        ownerLN(ln1g + l * 64, ln1b + l * 64);   // x = LN(rr + proj) -> rr, xb
        __syncthreads();

        // ================= FFN (2 chunks of 128 hidden cols) =================
        f32x4 facc[8];
        #pragma unroll
        for (int t = 0; t < 8; ++t) facc[t] = {0.f, 0.f, 0.f, 0.f};
        #pragma unroll
        for (int ch = 0; ch < 2; ++ch) {
            if (ch) __syncthreads();   // WAR on hb
            {   // FFN1 -> hb (relu): wave w = n-tile, all 16 m-tiles
                const unsigned short* Wt = w1t + l * 16384;
                int gcol = 128 * ch + 16 * w + cc;
                bf16x8 bf0 = *(const bf16x8*)&Wt[gcol * 64 + 8 * gg];
                bf16x8 bf1 = *(const bf16x8*)&Wt[gcol * 64 + 32 + 8 * gg];
                float bb = b1[l * 256 + gcol];
                #pragma unroll
                for (int mt = 0; mt < 16; ++mt) {
                    bf16x8 x0 = *(const bf16x8*)&xb[16 * mt + cc][8 * gg];
                    bf16x8 x1 = *(const bf16x8*)&xb[16 * mt + cc][32 + 8 * gg];
                    f32x4 c = {0.f, 0.f, 0.f, 0.f};
                    c = MFMA16(x0, bf0, c);
                    c = MFMA16(x1, bf1, c);
                    #pragma unroll
                    for (int r = 0; r < 4; ++r)
                        hb[16 * mt + 4 * gg + r][16 * w + cc] = f2b1(fmaxf(c[r] + bb, 0.f));
                }
            }
            __syncthreads();
            {   // FFN2 accumulate
                const unsigned short* Wt = w2t + l * 16384;
                int n = w & 3;
                #pragma unroll
                for (int ks = 0; ks < 4; ++ks) {
                    bf16x8 bf0 = *(const bf16x8*)&Wt[(16 * n + cc) * 256 + 128 * ch + 32 * ks + 8 * gg];
                    #pragma unroll
                    for (int mi = 0; mi < 8; ++mi) {
                        int mt = 8 * (w >> 2) + mi;
                        bf16x8 h0 = *(const bf16x8*)&hb[16 * mt + cc][32 * ks + 8 * gg];
                        facc[mi] = MFMA16(h0, bf0, facc[mi]);
                    }
                }
            }
        }
        __syncthreads();   // last hb reads done (hb aliases proj)
        {   // FFN2 epilogue -> proj
            int n = w & 3;
            float bb = b2[l * 64 + 16 * n + cc];
            #pragma unroll
            for (int mi = 0; mi < 8; ++mi) {
                int mt = 8 * (w >> 2) + mi;
                #pragma unroll
                for (int r = 0; r < 4; ++r)
                    proj[16 * mt + 4 * gg + r][16 * n + cc] = f2b1(facc[mi][r] + bb);
            }
        }
        __syncthreads();
        ownerLN(ln2g + l * 64, ln2b + l * 64);   // x = LN(rr + proj) -> rr, xb
        __syncthreads();
    } // layers

    // ================= logits (80 tiles = 16 m x 5 n; 10 per wave) =================
    #pragma unroll
    for (int t = 0; t < 10; ++t) {
        int id = w + 8 * t;             // 0..79
        int n = id >> 4, mt = id & 15;
        bf16x8 a0 = *(const bf16x8*)&xb[16 * mt + cc][8 * gg];
        bf16x8 a1 = *(const bf16x8*)&xb[16 * mt + cc][32 + 8 * gg];
        bf16x8 bf0 = *(const bf16x8*)&woutt[(16 * n + cc) * 64 + 8 * gg];
        bf16x8 bf1 = *(const bf16x8*)&woutt[(16 * n + cc) * 64 + 32 + 8 * gg];
        f32x4 c = {0.f, 0.f, 0.f, 0.f};
        c = MFMA16(a0, bf0, c);
        c = MFMA16(a1, bf1, c);
        int col = 16 * n + cc;
        if (col < 65) {
            float bb = bout[col];
            #pragma unroll
            for (int r = 0; r < 4; ++r) {
                int row = 16 * mt + 4 * gg + r;
                float v = c[r] + bb;
                out_logits[((size_t)b * 256 + row) * 65 + col] = v;
                proj[row][col] = f2b1(v);   // stage for loss
            }
        }
    }
    __syncthreads();

    // ================= loss partial =================
    {
        float sum = 0.f;
        for (int c2 = lq; c2 < 65; c2 += 2) sum += __expf(b2f(proj[lrow][c2]));
        sum += __shfl_xor(sum, 1, 64);
        float nll = 0.f;
        if (lq == 0) {
            int lab = labels[b * 256 + lrow];
            nll = logf(sum) - b2f(proj[lrow][lab]);
        }
        #pragma unroll
        for (int m = 1; m < 64; m <<= 1) nll += __shfl_xor(nll, m, 64);
        if (lane == 0) red[w] = nll;
        __syncthreads();
        if (tid == 0) {
            float s = 0.f;
            #pragma unroll
            for (int i = 0; i < 8; ++i) s += red[i];
            partials[b] = s;
        }
    }
}

__global__ __launch_bounds__(64)
void loss_reduce(const float* __restrict__ partials, float* __restrict__ out) {
    int t = threadIdx.x;
    float s = partials[t] + partials[t + 64] + partials[t + 128] + partials[t + 192];
    #pragma unroll
    for (int m = 1; m < 64; m <<= 1) s += __shfl_xor(s, m, 64);
    if (t == 0) out[0] = s * (1.f / 65536.f);
}

// ---------------- host ----------------
extern "C" void kernel_launch(void* const* d_in, const int* in_sizes, int n_in,
                              void* d_out, int out_size, void* d_ws, size_t ws_size,
                              hipStream_t stream) {
    const int*   inputs = (const int*)d_in[0];
    const int*   labels = (const int*)d_in[1];
    const float* emb  = (const float*)d_in[2];
    const float* Wq   = (const float*)d_in[3];
    const float* bq   = (const float*)d_in[4];
    const float* Wk   = (const float*)d_in[5];
    const float* bk   = (const float*)d_in[6];
    const float* Wv   = (const float*)d_in[7];
    const float* bv   = (const float*)d_in[8];
    const float* Wo   = (const float*)d_in[9];
    const float* bo   = (const float*)d_in[10];
    const float* ln1g = (const float*)d_in[11];
    const float* ln1b = (const float*)d_in[12];
    const float* ln2g = (const float*)d_in[13];
    const float* ln2b = (const float*)d_in[14];
    const float* W1   = (const float*)d_in[15];
    const float* b1   = (const float*)d_in[16];
    const float* W2   = (const float*)d_in[17];
    const float* b2   = (const float*)d_in[18];
    const float* Wout = (const float*)d_in[19];
    const float* bout = (const float*)d_in[20];

    float* logits = (float*)d_out;
    float* loss   = logits + (size_t)65536 * 65;

    float* partials = (float*)d_ws;
    unsigned short* wbuf = (unsigned short*)((char*)d_ws + 1024);

    prep_kernel<<<dim3(192, 7), 256, 0, stream>>>(Wq, Wk, Wv, Wo, W1, W2, Wout, wbuf);
    tf_kernel<<<NBATCH, 512, 0, stream>>>(inputs, labels, emb,
                                          bq, bk, bv, bo,
                                          ln1g, ln1b, ln2g, ln2b,
                                          b1, b2, bout,
                                          wbuf, logits, partials);
    loss_reduce<<<1, 64, 0, stream>>>(partials, loss);
}